// Round 9
// baseline (1079.559 us; speedup 1.0000x reference)
//
#include <hip/hip_runtime.h>
#include <hip/hip_bf16.h>

typedef __attribute__((ext_vector_type(8))) short short8;
typedef __attribute__((ext_vector_type(4))) float f32x4;

__device__ __forceinline__ float b2f(ushort u){ unsigned v = ((unsigned)u)<<16; float f; __builtin_memcpy(&f,&v,4); return f; }
__device__ __forceinline__ ushort f2b(float x){ __hip_bfloat16 h = __float2bfloat16(x); ushort u; __builtin_memcpy(&u,&h,2); return u; }
__device__ __forceinline__ float lrelu(float x){ return x >= 0.f ? x : 0.2f*x; }

// ---------------- small prep kernels ----------------

__global__ void k_zero(int* degi, long N, int* cntE, float* loopS, long NE){
  long i = (long)blockIdx.x*256 + threadIdx.x;
  if (i < N) degi[i] = 0;
  if (i < NE) { cntE[i] = 0; loopS[i] = 0.f; }
}

__global__ void k_deg_val(const int* __restrict__ ve, long E2, int* degi){
  long e = (long)blockIdx.x*256 + threadIdx.x;
  if (e < E2) atomicAdd(&degi[ve[2*e+1]], 1);
}

__global__ void k_deg_ent(const int* __restrict__ ee, const float* __restrict__ lab, long E1, int* cntE, float* loopS){
  long e = (long)blockIdx.x*256 + threadIdx.x;
  if (e < E1){ int d = ee[2*e+1]; atomicAdd(&cntE[d],1); atomicAdd(&loopS[d], lab[e]); }
}

__global__ void k_dinv(const int* degi, float* dinv, long N, const int* cntE, const float* loopS, float* loopA, long NE){
  long n = (long)blockIdx.x*256 + threadIdx.x;
  if (n < N) dinv[n] = rsqrtf((float)(degi[n]+1));
  if (n < NE) loopA[n] = loopS[n] / fmaxf((float)cntE[n], 1.f);
}

// ---------------- prefix-sum (CSR rowptr) ----------------
__global__ void k_scan1(const int* __restrict__ deg, long L, int* __restrict__ ps, int* __restrict__ bsum){
  __shared__ int s[256];
  long base = (long)blockIdx.x*1024;
  int t = threadIdx.x;
  int v[4]; int sum = 0;
#pragma unroll
  for (int i=0;i<4;++i){ long idx = base + t*4 + i; v[i] = (idx<L) ? deg[idx] : 0; sum += v[i]; }
  s[t] = sum; __syncthreads();
  for (int off=1; off<256; off<<=1){
    int x = 0;
    if (t>=off) x = s[t-off];
    __syncthreads();
    if (t>=off) s[t] += x;
    __syncthreads();
  }
  int run = s[t] - sum;
#pragma unroll
  for (int i=0;i<4;++i){ long idx = base + t*4 + i; if (idx<L) ps[idx] = run; run += v[i]; }
  if (t==255) bsum[blockIdx.x] = s[255];
}

__global__ void k_scan2(const int* __restrict__ bsum, int* __restrict__ boff, int nb){
  __shared__ int s[512];
  int t = threadIdx.x;
  int v = (t<nb) ? bsum[t] : 0;
  s[t] = v; __syncthreads();
  for (int off=1; off<512; off<<=1){
    int x = 0;
    if (t>=off) x = s[t-off];
    __syncthreads();
    if (t>=off) s[t] += x;
    __syncthreads();
  }
  if (t<nb) boff[t] = s[t] - v;
}

__global__ void k_scan3(int* __restrict__ ps, int* __restrict__ cur, const int* __restrict__ boff, long L, int E){
  long i = (long)blockIdx.x*256 + threadIdx.x;
  if (i < L){ int v = ps[i] + boff[i>>10]; ps[i] = v; cur[i] = v; }
  if (i == L) ps[L] = E;
}

__global__ void k_scatter_val(const int* __restrict__ ve, long E2, const float* __restrict__ dinv,
                              int* __restrict__ cur, int2* __restrict__ pk){
  long e = (long)blockIdx.x*256 + threadIdx.x;
  if (e >= E2) return;
  int s = ve[2*e], d = ve[2*e+1];
  int pos = atomicAdd(&cur[d], 1);
  int2 p; p.x = s; p.y = __float_as_int(dinv[s]);
  pk[pos] = p;
}

__global__ void k_scatter_ent(const int* __restrict__ ee, const float* __restrict__ lab, long E1,
                              int* __restrict__ cur, int2* __restrict__ pk){
  long e = (long)blockIdx.x*256 + threadIdx.x;
  if (e >= E1) return;
  int s = ee[2*e], d = ee[2*e+1];
  int pos = atomicAdd(&cur[d], 1);
  int2 p; p.x = s; p.y = __float_as_int(lab[e]);
  pk[pos] = p;
}

// ---------------- tiny weight-chain prep ----------------

// Wvt[n*128+k] = bf16(W[(128+k)*128+n])
__global__ void k_wvt(const float* __restrict__ W, ushort* __restrict__ Wvt){
  int o = blockIdx.x*256 + threadIdx.x; int k = o>>7, n = o&127;
  Wvt[n*128+k] = f2b(W[(128+k)*128+n]);
}

// C = A@B (128x128 fp32)
__global__ void k_mm128(const float* __restrict__ A, const float* __restrict__ B, float* __restrict__ C){
  int o = blockIdx.x*256 + threadIdx.x; int k = o>>7, n = o&127;
  float s = 0.f;
  for (int j=0;j<128;++j) s += A[k*128+j]*B[j*128+n];
  C[o] = s;
}

// Mt[n*128+k] = bf16(sum_j P[k][j]*Wl[j][n])   (transposed for GEMM B-operand)
__global__ void k_mmt(const float* __restrict__ P, const float* __restrict__ Wl, ushort* __restrict__ Mt){
  int o = blockIdx.x*256 + threadIdx.x; int k = o>>7, n = o&127;
  float s = 0.f;
  for (int j=0;j<128;++j) s += P[k*128+j]*Wl[j*128+n];
  Mt[n*128+k] = f2b(s);
}

// u_k = (g1b@G2)@Wl_k ; v_k = g2b@Wl_k
__global__ void k_uv(const float* g1b, const float* g2b, const float* G2,
                     const float* Wl1, const float* Wl2,
                     float* u1, float* v1, float* u2, float* v2){
  __shared__ float t[128];
  int n = threadIdx.x; // 128
  float s = 0.f;
  for (int k=0;k<128;++k) s += g1b[k]*G2[k*128+n];
  t[n] = s; __syncthreads();
  float a=0.f,b=0.f,c=0.f,dd=0.f;
  for (int j=0;j<128;++j){
    float w1 = Wl1[j*128+n], w2 = Wl2[j*128+n];
    a += t[j]*w1; c += t[j]*w2; b += g2b[j]*w1; dd += g2b[j]*w2;
  }
  u1[n]=a; v1[n]=b; u2[n]=c; v2[n]=dd;
}

__global__ void k_csc(const float* We1, const float* ae1, const float* We2, const float* ae2, float* csc){
  int t = threadIdx.x; // 128
  __shared__ float s1[128], s2[128];
  s1[t] = We1[t]*ae1[t];
  s2[t] = We2[t]*ae2[t];
  __syncthreads();
  for (int off=64; off>0; off>>=1){ if (t<off){ s1[t]+=s1[t+off]; s2[t]+=s2[t+off]; } __syncthreads(); }
  if (t==0){ csc[0]=s1[0]; csc[1]=s2[0]; }
}

// attP[a][n] = sum_j att[a][j] * W[j][n]   (W rows 0..127 = attribute part)
__global__ void k_attP(const float* __restrict__ att, const float* __restrict__ W, float* attP, long NA){
  long o = (long)blockIdx.x*256 + threadIdx.x;
  if (o >= NA*128) return;
  long a = o>>7; int n = o&127;
  float s = 0.f;
  for (int j=0;j<128;++j) s += att[a*128+j]*W[j*128+n];
  attP[o] = s;
}

// fp32 -> bf16 bulk cast (n4 float4 groups)
__global__ void k_cast(const float* __restrict__ in, ushort* __restrict__ out, long n4){
  long i = (long)blockIdx.x*256 + threadIdx.x;
  if (i >= n4) return;
  float4 v = ((const float4*)in)[i];
  ushort4 o; o.x=f2b(v.x); o.y=f2b(v.y); o.z=f2b(v.z); o.w=f2b(v.w);
  ((ushort4*)out)[i] = o;
}

// ---------------- MFMA GEMM: C[M x 128] (bf16) = A[M x 128] @ Bt^T (+ rs*u + v) ----------------
// Optional fused attention dots: alsO/aldO get (x . asv), (x . adv) per row into .x (layer 0) or .y (layer 1).
template<bool AF32>
__global__ __launch_bounds__(256) void k_gemm(const void* __restrict__ Ap, const ushort* __restrict__ Bt,
                                              ushort* __restrict__ C, long M, int ostride, int ooff,
                                              const float* __restrict__ u, const float* __restrict__ v,
                                              const float* __restrict__ rs,
                                              const float* __restrict__ asv, const float* __restrict__ adv,
                                              float2* __restrict__ alsO, float2* __restrict__ aldO, int layer){
  __shared__ ushort As[128*128];
  __shared__ ushort Bs[128*128];
  __shared__ float sAls[128], sAld[128];
  int tid = threadIdx.x;
  long m0 = (long)blockIdx.x * 128;
  if (asv && tid < 128){ sAls[tid] = 0.f; sAld[tid] = 0.f; }
  {
    const int4* Bg = (const int4*)Bt;
#pragma unroll
    for (int it=0; it<8; ++it){
      int chunk = tid + it*256;
      int row = chunk >> 4, c = chunk & 15;
      int4 vv = Bg[chunk];
      *(int4*)&Bs[(row<<7) + (((c ^ row) & 15)<<3)] = vv;
    }
  }
  if (AF32){
    const float4* Ag = (const float4*)Ap;
#pragma unroll
    for (int it=0; it<16; ++it){
      int chunk = tid + it*256;
      int row = chunk >> 5, q = chunk & 31;
      long grow = m0 + row;
      float4 vv = make_float4(0.f,0.f,0.f,0.f);
      if (grow < M) vv = Ag[grow*32 + q];
      ushort4 h; h.x=f2b(vv.x); h.y=f2b(vv.y); h.z=f2b(vv.z); h.w=f2b(vv.w);
      int c16 = q >> 1, half = q & 1;
      *(ushort4*)&As[(row<<7) + (((c16 ^ row)&15)<<3) + (half<<2)] = h;
    }
  } else {
    const int4* Ag = (const int4*)Ap;
#pragma unroll
    for (int it=0; it<8; ++it){
      int chunk = tid + it*256;
      int row = chunk >> 4, c = chunk & 15;
      long grow = m0 + row;
      int4 vv = make_int4(0,0,0,0);
      if (grow < M) vv = Ag[grow*16 + c];
      *(int4*)&As[(row<<7) + (((c ^ row)&15)<<3)] = vv;
    }
  }
  __syncthreads();
  int wave = tid >> 6, lane = tid & 63;
  int wm = (wave & 1) << 6, wn = (wave >> 1) << 6;
  int l15 = lane & 15, quad = lane >> 4;
  f32x4 acc[4][4] = {};
#pragma unroll
  for (int kk=0; kk<4; ++kk){
    int ch = (kk<<2) + quad;
    short8 a[4], b[4];
#pragma unroll
    for (int i=0;i<4;++i){ int r = wm + (i<<4) + l15; a[i] = *(const short8*)&As[(r<<7) + (((ch ^ r)&15)<<3)]; }
#pragma unroll
    for (int j=0;j<4;++j){ int r = wn + (j<<4) + l15; b[j] = *(const short8*)&Bs[(r<<7) + (((ch ^ r)&15)<<3)]; }
#pragma unroll
    for (int i=0;i<4;++i)
#pragma unroll
      for (int j=0;j<4;++j)
        acc[i][j] = __builtin_amdgcn_mfma_f32_16x16x32_bf16(a[i], b[j], acc[i][j], 0,0,0);
  }
#pragma unroll
  for (int i=0;i<4;++i){
#pragma unroll
    for (int r=0;r<4;++r){
      int lrow = wm + (i<<4) + (quad<<2) + r;
      long grow = m0 + lrow;
      if (grow < M){
        float rsv = rs ? rs[grow] : 0.f;
        float pAls = 0.f, pAld = 0.f;
#pragma unroll
        for (int j=0;j<4;++j){
          int col = wn + (j<<4) + l15;
          float x = acc[i][j][r];
          if (u) x += rsv*u[col] + v[col];
          if (asv){ pAls += x*asv[col]; pAld += x*adv[col]; }
          C[grow*(long)ostride + ooff + col] = f2b(x);
        }
        if (asv){ atomicAdd(&sAls[lrow], pAls); atomicAdd(&sAld[lrow], pAld); }
      }
    }
  }
  if (asv){
    __syncthreads();
    if (tid < 128){
      long grow = m0 + tid;
      if (grow < M){
        if (layer == 0){ alsO[grow].x = sAls[tid]; aldO[grow].x = sAld[tid]; }
        else           { alsO[grow].y = sAls[tid]; aldO[grow].y = sAld[tid]; }
      }
    }
  }
}

// ---------------- gather / aggregation ----------------

__global__ void k_gather(const int* __restrict__ trip, const float* __restrict__ attP,
                         const ushort* __restrict__ valP, ushort* __restrict__ h0, long T, long NEnt){
  int w = threadIdx.x >> 6, lane = threadIdx.x & 63;
  long t = (long)blockIdx.x*4 + w;
  if (t >= T) return;
  int a = trip[3*t+2], v = trip[3*t+1];
  float2 ap = ((const float2*)(attP + (long)a*128))[lane];
  unsigned vp = ((const unsigned*)(valP + (long)v*128))[lane];
  ushort2 o;
  o.x = f2b(ap.x + b2f((ushort)(vp & 0xffff)));
  o.y = f2b(ap.y + b2f((ushort)(vp >> 16)));
  ((ushort2*)(h0 + (NEnt + t)*128))[lane] = o;
}

// out[d] = dinv[d]^2*h[d] + sum_e dinv[s]*dinv[d]*h[s]   (bf16 out; optional rowsum rs)
// 2 dests per wave (32 lanes x uint2 per row) -> 2x per-wave MLP at degree~1.25;
// padded 4-wide pipelined gather within each 32-lane group.
__global__ void k_agg(const int* __restrict__ rp, const int2* __restrict__ pk,
                      const ushort* __restrict__ h, const float* __restrict__ dinv,
                      ushort* __restrict__ outH, float* __restrict__ rs, long R){
  int g = threadIdx.x>>5, l = threadIdx.x&31;   // 8 groups of 32 lanes per block
  long d = (long)blockIdx.x*8 + g;
  if (d >= R) return;
  int base = (g&1)<<5;                           // group's lane base within its wave
  int r0 = rp[d], r1 = rp[d+1], ne = r1 - r0;
  float dv = dinv[d];
  uint2 hv = ((const uint2*)(h + d*128))[l];
  float wE = 0.f; int srcc = 0;
  if (l < ne){ int2 p = pk[r0 + l]; srcc = p.x; wE = dv * __int_as_float(p.y); }
  float wself = dv*dv;
  float a0 = wself*b2f((ushort)(hv.x&0xffff));
  float a1 = wself*b2f((ushort)(hv.x>>16));
  float a2 = wself*b2f((ushort)(hv.y&0xffff));
  float a3 = wself*b2f((ushort)(hv.y>>16));
  float wsum = wself;
  int lim = ne < 32 ? ne : 32;
  for (int j = 0; j < lim; j += 4){
    int i1 = (j+1<lim)? j+1 : lim-1;
    int i2 = (j+2<lim)? j+2 : lim-1;
    int i3 = (j+3<lim)? j+3 : lim-1;
    float w0=__shfl(wE,base+j),   w1=__shfl(wE,base+i1),   w2=__shfl(wE,base+i2),   w3=__shfl(wE,base+i3);
    int   s0=__shfl(srcc,base+j), s1=__shfl(srcc,base+i1), s2=__shfl(srcc,base+i2), s3=__shfl(srcc,base+i3);
    if (j+1>=lim) w1 = 0.f;
    if (j+2>=lim) w2 = 0.f;
    if (j+3>=lim) w3 = 0.f;
    uint2 v0 = ((const uint2*)(h + (long)s0*128))[l];
    uint2 v1 = ((const uint2*)(h + (long)s1*128))[l];
    uint2 v2 = ((const uint2*)(h + (long)s2*128))[l];
    uint2 v3 = ((const uint2*)(h + (long)s3*128))[l];
    wsum += w0+w1+w2+w3;
    a0 += w0*b2f((ushort)(v0.x&0xffff)) + w1*b2f((ushort)(v1.x&0xffff))
        + w2*b2f((ushort)(v2.x&0xffff)) + w3*b2f((ushort)(v3.x&0xffff));
    a1 += w0*b2f((ushort)(v0.x>>16)) + w1*b2f((ushort)(v1.x>>16))
        + w2*b2f((ushort)(v2.x>>16)) + w3*b2f((ushort)(v3.x>>16));
    a2 += w0*b2f((ushort)(v0.y&0xffff)) + w1*b2f((ushort)(v1.y&0xffff))
        + w2*b2f((ushort)(v2.y&0xffff)) + w3*b2f((ushort)(v3.y&0xffff));
    a3 += w0*b2f((ushort)(v0.y>>16)) + w1*b2f((ushort)(v1.y>>16))
        + w2*b2f((ushort)(v2.y>>16)) + w3*b2f((ushort)(v3.y>>16));
  }
  for (int e = r0+32; e < r1; ++e){   // rare deg>32
    int2 p = pk[e];
    float wgt = dv * __int_as_float(p.y);
    uint2 sv = ((const uint2*)(h + (long)p.x*128))[l];
    a0 += wgt * b2f((ushort)(sv.x&0xffff));
    a1 += wgt * b2f((ushort)(sv.x>>16));
    a2 += wgt * b2f((ushort)(sv.y&0xffff));
    a3 += wgt * b2f((ushort)(sv.y>>16));
    wsum += wgt;
  }
  ushort4 o; o.x = f2b(a0); o.y = f2b(a1); o.z = f2b(a2); o.w = f2b(a3);
  ((ushort4*)(outH + d*128))[l] = o;
  if (rs && l==0) rs[d] = wsum;
}

// Fused dual-layer GAT via CSR gather over interleaved hgI; writes final out (+b1+b2+ent_feats)
// batch0 accumulate loop: padded 4-wide pipelined (no serial remainder).
__global__ void k_gat_csr(const int* __restrict__ rp, const int2* __restrict__ pk,
      const uint2* __restrict__ hgI,
      const float2* __restrict__ alsP, const float2* __restrict__ aldP,
      const float* __restrict__ loopA, const float* __restrict__ csc,
      const float* __restrict__ b1, const float* __restrict__ b2v,
      const float* __restrict__ entf, float* __restrict__ out, long R){
  int w = threadIdx.x>>6, lane = threadIdx.x&63;
  long d = (long)blockIdx.x*4 + w;
  if (d >= R) return;
  int r0 = rp[d], r1 = rp[d+1], ne = r1 - r0;
  float c1 = csc[0], c2 = csc[1];
  float2 aldd = aldP[d];
  float2 alsd = alsP[d];
  float la = loopA[d];
  float a1s = lrelu(alsd.x + aldd.x + c1*la);
  float a2s = lrelu(alsd.y + aldd.y + c2*la);
  // batch0 edge alphas, cached in registers
  float a1c = -1e30f, a2c = -1e30f; int srcc = 0;
  if (lane < ne){
    int2 p = pk[r0+lane];
    float lab = __int_as_float(p.y);
    float2 av = alsP[p.x];
    a1c = lrelu(av.x + aldd.x + c1*lab);
    a2c = lrelu(av.y + aldd.y + c2*lab);
    srcc = p.x;
  }
  float m1 = a1c, m2 = a2c;
  for (int o=32;o>0;o>>=1){ m1 = fmaxf(m1,__shfl_down(m1,o)); m2 = fmaxf(m2,__shfl_down(m2,o)); }
  m1 = fmaxf(__shfl(m1,0), a1s); m2 = fmaxf(__shfl(m2,0), a2s);
  for (int base=64; base<ne; base+=64){   // rare (deg>64)
    int i = base+lane; float x1=-1e30f, x2=-1e30f;
    if (i<ne){ int2 p = pk[r0+i]; float lab = __int_as_float(p.y); float2 av = alsP[p.x];
      x1 = lrelu(av.x + aldd.x + c1*lab); x2 = lrelu(av.y + aldd.y + c2*lab); }
    for (int o=32;o>0;o>>=1){ x1 = fmaxf(x1,__shfl_down(x1,o)); x2 = fmaxf(x2,__shfl_down(x2,o)); }
    m1 = fmaxf(m1, __shfl(x1,0)); m2 = fmaxf(m2, __shfl(x2,0));
  }
  float e1s = __expf(a1s-m1), e2s = __expf(a2s-m2);
  float z1 = e1s, z2 = e2s;
  bool lo = lane < 32;
  uint2 hv = hgI[d*64 + lane];
  float ws0 = lo ? e1s : e2s;
  float ac0 = ws0*b2f((ushort)(hv.x&0xffff));
  float ac1 = ws0*b2f((ushort)(hv.x>>16));
  float ac2 = ws0*b2f((ushort)(hv.y&0xffff));
  float ac3 = ws0*b2f((ushort)(hv.y>>16));
  {
    float e1 = (lane<ne) ? __expf(a1c-m1) : 0.f;
    float e2 = (lane<ne) ? __expf(a2c-m2) : 0.f;
    int lim = ne < 64 ? ne : 64;
    for (int j = 0; j < lim; j += 4){
      int i1 = (j+1<lim)? j+1 : lim-1;
      int i2 = (j+2<lim)? j+2 : lim-1;
      int i3 = (j+3<lim)? j+3 : lim-1;
      float f1a=__shfl(e1,j),   f1b=__shfl(e1,i1),  f1c=__shfl(e1,i2),  f1d=__shfl(e1,i3);
      float f2a=__shfl(e2,j),   f2bb=__shfl(e2,i1), f2c=__shfl(e2,i2),  f2d=__shfl(e2,i3);
      int   sa=__shfl(srcc,j),  sb=__shfl(srcc,i1), sc=__shfl(srcc,i2), sd=__shfl(srcc,i3);
      if (j+1>=lim){ f1b = 0.f; f2bb = 0.f; }
      if (j+2>=lim){ f1c = 0.f; f2c = 0.f; }
      if (j+3>=lim){ f1d = 0.f; f2d = 0.f; }
      uint2 va = hgI[(long)sa*64 + lane];
      uint2 vb = hgI[(long)sb*64 + lane];
      uint2 vc = hgI[(long)sc*64 + lane];
      uint2 vd = hgI[(long)sd*64 + lane];
      z1 += f1a+f1b+f1c+f1d; z2 += f2a+f2bb+f2c+f2d;
      float fa = lo ? f1a : f2a, fb = lo ? f1b : f2bb, fc = lo ? f1c : f2c, fd = lo ? f1d : f2d;
      ac0 += fa*b2f((ushort)(va.x&0xffff)) + fb*b2f((ushort)(vb.x&0xffff))
           + fc*b2f((ushort)(vc.x&0xffff)) + fd*b2f((ushort)(vd.x&0xffff));
      ac1 += fa*b2f((ushort)(va.x>>16)) + fb*b2f((ushort)(vb.x>>16))
           + fc*b2f((ushort)(vc.x>>16)) + fd*b2f((ushort)(vd.x>>16));
      ac2 += fa*b2f((ushort)(va.y&0xffff)) + fb*b2f((ushort)(vb.y&0xffff))
           + fc*b2f((ushort)(vc.y&0xffff)) + fd*b2f((ushort)(vd.y&0xffff));
      ac3 += fa*b2f((ushort)(va.y>>16)) + fb*b2f((ushort)(vb.y>>16))
           + fc*b2f((ushort)(vc.y>>16)) + fd*b2f((ushort)(vd.y>>16));
    }
  }
  for (int base=64; base<ne; base+=64){   // rare
    int i = base+lane; float e1=0.f, e2=0.f; int src = 0;
    if (i<ne){ int2 p = pk[r0+i]; float lab = __int_as_float(p.y); float2 av = alsP[p.x];
      e1 = __expf(lrelu(av.x + aldd.x + c1*lab)-m1);
      e2 = __expf(lrelu(av.y + aldd.y + c2*lab)-m2);
      src = p.x; }
    int lim2 = (ne-base < 64) ? (ne-base) : 64;
    for (int j2=0;j2<lim2;++j2){
      float f1 = __shfl(e1,j2), f2 = __shfl(e2,j2); int sj = __shfl(src,j2);
      z1 += f1; z2 += f2;
      uint2 vv = hgI[(long)sj*64 + lane];
      float f = lo ? f1 : f2;
      ac0 += f*b2f((ushort)(vv.x&0xffff));
      ac1 += f*b2f((ushort)(vv.x>>16));
      ac2 += f*b2f((ushort)(vv.y&0xffff));
      ac3 += f*b2f((ushort)(vv.y>>16));
    }
  }
  float iz = lo ? 1.f/(z1+1e-16f) : 1.f/(z2+1e-16f);
  ac0 *= iz; ac1 *= iz; ac2 *= iz; ac3 *= iz;
  int pl = lane ^ 32;
  float p0 = __shfl(ac0, pl), p1 = __shfl(ac1, pl), p2 = __shfl(ac2, pl), p3 = __shfl(ac3, pl);
  if (lo){
    float4 bb1 = ((const float4*)b1)[lane];
    float4 bb2 = ((const float4*)b2v)[lane];
    float4 ef  = ((const float4*)(entf + d*128))[lane];
    float4 o;
    o.x = ac0 + p0 + bb1.x + bb2.x + ef.x;
    o.y = ac1 + p1 + bb1.y + bb2.y + ef.y;
    o.z = ac2 + p2 + bb1.z + bb2.z + ef.z;
    o.w = ac3 + p3 + bb1.w + bb2.w + ef.w;
    ((float4*)(out + d*128))[lane] = o;
  }
}

// ---------------- host ----------------

extern "C" void kernel_launch(void* const* d_in, const int* in_sizes, int n_in,
                              void* d_out, int out_size, void* d_ws, size_t ws_size,
                              hipStream_t stream) {
  const int*   trip = (const int*)d_in[0];
  const int*   ee   = (const int*)d_in[1];
  const float* eel  = (const float*)d_in[2];
  const int*   ve   = (const int*)d_in[3];
  const float* att  = (const float*)d_in[5];
  const float* valf = (const float*)d_in[6];
  const float* entf = (const float*)d_in[7];
  const float* W    = (const float*)d_in[8];
  const float* G1   = (const float*)d_in[9];
  const float* g1b  = (const float*)d_in[10];
  const float* G2   = (const float*)d_in[11];
  const float* g2b  = (const float*)d_in[12];
  const float* Wl1  = (const float*)d_in[13];
  const float* as1v = (const float*)d_in[14];
  const float* ad1v = (const float*)d_in[15];
  const float* We1  = (const float*)d_in[16];
  const float* ae1  = (const float*)d_in[17];
  const float* b1   = (const float*)d_in[18];
  const float* Wl2  = (const float*)d_in[19];
  const float* as2v = (const float*)d_in[20];
  const float* ad2v = (const float*)d_in[21];
  const float* We2  = (const float*)d_in[22];
  const float* ae2  = (const float*)d_in[23];
  const float* b2   = (const float*)d_in[24];

  long T    = in_sizes[0]/3;
  long E1   = in_sizes[1]/2;
  long E2   = in_sizes[3]/2;
  long NA   = in_sizes[5]/128;
  long NV   = in_sizes[6]/128;
  long NEnt = in_sizes[7]/128;
  long N    = NEnt + T;

  size_t off = 0;
  auto alloc = [&](size_t bytes)->char*{
    char* p = (char*)d_ws + off; off = (off + bytes + 255) & ~(size_t)255; return p;
  };
  ushort* nodes0 = (ushort*)alloc((size_t)N*128*2);   // later reused as hgI (NEnt*256 ushorts)
  ushort* y1     = (ushort*)alloc((size_t)N*128*2);   // valP overlays this before y1 is written
  ushort* y2     = (ushort*)alloc((size_t)NEnt*128*2);
  float*  attP   = (float*)alloc((size_t)NA*128*4);
  int*    degi   = (int*)alloc(N*4);
  float*  dinv   = (float*)alloc(N*4);
  int*    cntE   = (int*)alloc(NEnt*4);
  float*  loopS  = (float*)alloc(NEnt*4);
  float*  loopA  = (float*)alloc(NEnt*4);
  float2* alsP   = (float2*)alloc(NEnt*8);
  float2* aldP   = (float2*)alloc(NEnt*8);
  float*  rs     = (float*)alloc(NEnt*4);
  int*    rpV    = (int*)alloc((N+1)*4);
  int*    curV   = (int*)alloc(N*4);
  int2*   pkV    = (int2*)alloc((size_t)E2*8);
  int*    rpE    = (int*)alloc((NEnt+1)*4);
  int*    curE   = (int*)alloc(NEnt*4);
  int2*   pkE    = (int2*)alloc((size_t)E1*8);
  int*    bsumV  = (int*)alloc(512*4);
  int*    boffV  = (int*)alloc(512*4);
  int*    bsumE  = (int*)alloc(512*4);
  int*    boffE  = (int*)alloc(512*4);
  ushort* Wvt    = (ushort*)alloc(16384*2);
  float*  P      = (float*)alloc(16384*4);
  ushort* M1t    = (ushort*)alloc(16384*2);
  ushort* M2t    = (ushort*)alloc(16384*2);
  float*  u1     = (float*)alloc(128*4);
  float*  v1     = (float*)alloc(128*4);
  float*  u2     = (float*)alloc(128*4);
  float*  v2     = (float*)alloc(128*4);
  float*  csc    = (float*)alloc(256);

  ushort* valP = y1;                 // dead before y1 is written
  ushort* hgI  = nodes0;             // dead after y1 aggregation

  auto cdiv = [](long a, long b)->int{ return (int)((a + b - 1)/b); };
  int nbV = cdiv(N, 1024), nbE = cdiv(NEnt, 1024);

  // degrees / loop_attr
  k_zero<<<cdiv(N,256),256,0,stream>>>(degi, N, cntE, loopS, NEnt);
  k_deg_val<<<cdiv(E2,256),256,0,stream>>>(ve, E2, degi);
  k_deg_ent<<<cdiv(E1,256),256,0,stream>>>(ee, eel, E1, cntE, loopS);
  k_dinv<<<cdiv(N,256),256,0,stream>>>(degi, dinv, N, cntE, loopS, loopA, NEnt);

  // CSR build
  k_scan1<<<nbV,256,0,stream>>>(degi, N, rpV, bsumV);
  k_scan2<<<1,512,0,stream>>>(bsumV, boffV, nbV);
  k_scan3<<<cdiv(N+1,256),256,0,stream>>>(rpV, curV, boffV, N, (int)E2);
  k_scan1<<<nbE,256,0,stream>>>(cntE, NEnt, rpE, bsumE);
  k_scan2<<<1,512,0,stream>>>(bsumE, boffE, nbE);
  k_scan3<<<cdiv(NEnt+1,256),256,0,stream>>>(rpE, curE, boffE, NEnt, (int)E1);
  k_scatter_val<<<cdiv(E2,256),256,0,stream>>>(ve, E2, dinv, curV, pkV);
  k_scatter_ent<<<cdiv(E1,256),256,0,stream>>>(ee, eel, E1, curE, pkE);

  // tiny weight chains: P=G1@G2, M_k = P@Wl_k (bf16,T), u_k=(g1b@G2)@Wl_k, v_k=g2b@Wl_k
  k_wvt<<<64,256,0,stream>>>(W, Wvt);
  k_mm128<<<64,256,0,stream>>>(G1, G2, P);
  k_mmt<<<64,256,0,stream>>>(P, Wl1, M1t);
  k_mmt<<<64,256,0,stream>>>(P, Wl2, M2t);
  k_uv<<<1,128,0,stream>>>(g1b, g2b, G2, Wl1, Wl2, u1, v1, u2, v2);
  k_csc<<<1,128,0,stream>>>(We1, ae1, We2, ae2, csc);
  k_attP<<<cdiv(NA*128,256),256,0,stream>>>(att, W, attP, NA);

  // nodes0 (bf16): ent rows = ent_feats; val rows = attP[a] + (valf@Wv)[v]
  k_gemm<true><<<cdiv(NV,128),256,0,stream>>>(valf, Wvt, valP, NV, 128, 0, nullptr, nullptr, nullptr,
                                              nullptr, nullptr, nullptr, nullptr, 0);
  k_cast<<<cdiv(NEnt*32,256),256,0,stream>>>(entf, nodes0, NEnt*32);
  k_gather<<<cdiv(T,4),256,0,stream>>>(trip, attP, valP, nodes0, T, NEnt);

  // y1 = A(nodes0) over all N ; y2 = A(y1) over NEnt rows (+rowsum rs)
  k_agg<<<cdiv(N,8),256,0,stream>>>(rpV, pkV, nodes0, dinv, y1, nullptr, N);
  k_agg<<<cdiv(NEnt,8),256,0,stream>>>(rpV, pkV, y1, dinv, y2, rs, NEnt);

  // hgI rows = [ y2@M1 + rs*u1 + v1 | y2@M2 + rs*u2 + v2 ]; attention dots fused into epilogue
  k_gemm<false><<<cdiv(NEnt,128),256,0,stream>>>(y2, M1t, (ushort*)hgI, NEnt, 256, 0,   u1, v1, rs,
                                                 as1v, ad1v, alsP, aldP, 0);
  k_gemm<false><<<cdiv(NEnt,128),256,0,stream>>>(y2, M2t, (ushort*)hgI, NEnt, 256, 128, u2, v2, rs,
                                                 as2v, ad2v, alsP, aldP, 1);

  // fused dual-layer GAT aggregation -> final output
  k_gat_csr<<<cdiv(NEnt,4),256,0,stream>>>(rpE, pkE, (const uint2*)hgI, alsP, aldP,
                                           loopA, csc, b1, b2, entf, (float*)d_out, NEnt);
}

// Round 10
// 1071.557 us; speedup vs baseline: 1.0075x; 1.0075x over previous
//
#include <hip/hip_runtime.h>
#include <hip/hip_bf16.h>

typedef __attribute__((ext_vector_type(8))) short short8;
typedef __attribute__((ext_vector_type(4))) float f32x4;

__device__ __forceinline__ float b2f(ushort u){ unsigned v = ((unsigned)u)<<16; float f; __builtin_memcpy(&f,&v,4); return f; }
__device__ __forceinline__ ushort f2b(float x){ __hip_bfloat16 h = __float2bfloat16(x); ushort u; __builtin_memcpy(&u,&h,2); return u; }
__device__ __forceinline__ float lrelu(float x){ return x >= 0.f ? x : 0.2f*x; }

// ---------------- small prep kernels ----------------

__global__ void k_zero(int* degi, long N, int* cntE, float* loopS, long NE){
  long i = (long)blockIdx.x*256 + threadIdx.x;
  if (i < N) degi[i] = 0;
  if (i < NE) { cntE[i] = 0; loopS[i] = 0.f; }
}

__global__ void k_deg_val(const int* __restrict__ ve, long E2, int* degi){
  long e = (long)blockIdx.x*256 + threadIdx.x;
  if (e < E2) atomicAdd(&degi[ve[2*e+1]], 1);
}

__global__ void k_deg_ent(const int* __restrict__ ee, const float* __restrict__ lab, long E1, int* cntE, float* loopS){
  long e = (long)blockIdx.x*256 + threadIdx.x;
  if (e < E1){ int d = ee[2*e+1]; atomicAdd(&cntE[d],1); atomicAdd(&loopS[d], lab[e]); }
}

__global__ void k_dinv(const int* degi, float* dinv, long N, const int* cntE, const float* loopS, float* loopA, long NE){
  long n = (long)blockIdx.x*256 + threadIdx.x;
  if (n < N) dinv[n] = rsqrtf((float)(degi[n]+1));
  if (n < NE) loopA[n] = loopS[n] / fmaxf((float)cntE[n], 1.f);
}

// ---------------- prefix-sum (CSR rowptr) ----------------
__global__ void k_scan1(const int* __restrict__ deg, long L, int* __restrict__ ps, int* __restrict__ bsum){
  __shared__ int s[256];
  long base = (long)blockIdx.x*1024;
  int t = threadIdx.x;
  int v[4]; int sum = 0;
#pragma unroll
  for (int i=0;i<4;++i){ long idx = base + t*4 + i; v[i] = (idx<L) ? deg[idx] : 0; sum += v[i]; }
  s[t] = sum; __syncthreads();
  for (int off=1; off<256; off<<=1){
    int x = 0;
    if (t>=off) x = s[t-off];
    __syncthreads();
    if (t>=off) s[t] += x;
    __syncthreads();
  }
  int run = s[t] - sum;
#pragma unroll
  for (int i=0;i<4;++i){ long idx = base + t*4 + i; if (idx<L) ps[idx] = run; run += v[i]; }
  if (t==255) bsum[blockIdx.x] = s[255];
}

__global__ void k_scan2(const int* __restrict__ bsum, int* __restrict__ boff, int nb){
  __shared__ int s[512];
  int t = threadIdx.x;
  int v = (t<nb) ? bsum[t] : 0;
  s[t] = v; __syncthreads();
  for (int off=1; off<512; off<<=1){
    int x = 0;
    if (t>=off) x = s[t-off];
    __syncthreads();
    if (t>=off) s[t] += x;
    __syncthreads();
  }
  if (t<nb) boff[t] = s[t] - v;
}

__global__ void k_scan3(int* __restrict__ ps, int* __restrict__ cur, const int* __restrict__ boff, long L, int E){
  long i = (long)blockIdx.x*256 + threadIdx.x;
  if (i < L){ int v = ps[i] + boff[i>>10]; ps[i] = v; cur[i] = v; }
  if (i == L) ps[L] = E;
}

__global__ void k_scatter_val(const int* __restrict__ ve, long E2, const float* __restrict__ dinv,
                              int* __restrict__ cur, int2* __restrict__ pk){
  long e = (long)blockIdx.x*256 + threadIdx.x;
  if (e >= E2) return;
  int s = ve[2*e], d = ve[2*e+1];
  int pos = atomicAdd(&cur[d], 1);
  int2 p; p.x = s; p.y = __float_as_int(dinv[s]);
  pk[pos] = p;
}

__global__ void k_scatter_ent(const int* __restrict__ ee, const float* __restrict__ lab, long E1,
                              int* __restrict__ cur, int2* __restrict__ pk){
  long e = (long)blockIdx.x*256 + threadIdx.x;
  if (e >= E1) return;
  int s = ee[2*e], d = ee[2*e+1];
  int pos = atomicAdd(&cur[d], 1);
  int2 p; p.x = s; p.y = __float_as_int(lab[e]);
  pk[pos] = p;
}

// ---------------- tiny weight-chain prep ----------------

// Wvt[n*128+k] = bf16(W[(128+k)*128+n])
__global__ void k_wvt(const float* __restrict__ W, ushort* __restrict__ Wvt){
  int o = blockIdx.x*256 + threadIdx.x; int k = o>>7, n = o&127;
  Wvt[n*128+k] = f2b(W[(128+k)*128+n]);
}

// C = A@B (128x128 fp32)
__global__ void k_mm128(const float* __restrict__ A, const float* __restrict__ B, float* __restrict__ C){
  int o = blockIdx.x*256 + threadIdx.x; int k = o>>7, n = o&127;
  float s = 0.f;
  for (int j=0;j<128;++j) s += A[k*128+j]*B[j*128+n];
  C[o] = s;
}

// Mt[n*128+k] = bf16(sum_j P[k][j]*Wl[j][n])   (transposed for GEMM B-operand)
__global__ void k_mmt(const float* __restrict__ P, const float* __restrict__ Wl, ushort* __restrict__ Mt){
  int o = blockIdx.x*256 + threadIdx.x; int k = o>>7, n = o&127;
  float s = 0.f;
  for (int j=0;j<128;++j) s += P[k*128+j]*Wl[j*128+n];
  Mt[n*128+k] = f2b(s);
}

// u_k = (g1b@G2)@Wl_k ; v_k = g2b@Wl_k
__global__ void k_uv(const float* g1b, const float* g2b, const float* G2,
                     const float* Wl1, const float* Wl2,
                     float* u1, float* v1, float* u2, float* v2){
  __shared__ float t[128];
  int n = threadIdx.x; // 128
  float s = 0.f;
  for (int k=0;k<128;++k) s += g1b[k]*G2[k*128+n];
  t[n] = s; __syncthreads();
  float a=0.f,b=0.f,c=0.f,dd=0.f;
  for (int j=0;j<128;++j){
    float w1 = Wl1[j*128+n], w2 = Wl2[j*128+n];
    a += t[j]*w1; c += t[j]*w2; b += g2b[j]*w1; dd += g2b[j]*w2;
  }
  u1[n]=a; v1[n]=b; u2[n]=c; v2[n]=dd;
}

__global__ void k_csc(const float* We1, const float* ae1, const float* We2, const float* ae2, float* csc){
  int t = threadIdx.x; // 128
  __shared__ float s1[128], s2[128];
  s1[t] = We1[t]*ae1[t];
  s2[t] = We2[t]*ae2[t];
  __syncthreads();
  for (int off=64; off>0; off>>=1){ if (t<off){ s1[t]+=s1[t+off]; s2[t]+=s2[t+off]; } __syncthreads(); }
  if (t==0){ csc[0]=s1[0]; csc[1]=s2[0]; }
}

// attP[a][n] = sum_j att[a][j] * W[j][n]   (W rows 0..127 = attribute part)
__global__ void k_attP(const float* __restrict__ att, const float* __restrict__ W, float* attP, long NA){
  long o = (long)blockIdx.x*256 + threadIdx.x;
  if (o >= NA*128) return;
  long a = o>>7; int n = o&127;
  float s = 0.f;
  for (int j=0;j<128;++j) s += att[a*128+j]*W[j*128+n];
  attP[o] = s;
}

// fp32 -> bf16 bulk cast (n4 float4 groups)
__global__ void k_cast(const float* __restrict__ in, ushort* __restrict__ out, long n4){
  long i = (long)blockIdx.x*256 + threadIdx.x;
  if (i >= n4) return;
  float4 v = ((const float4*)in)[i];
  ushort4 o; o.x=f2b(v.x); o.y=f2b(v.y); o.z=f2b(v.z); o.w=f2b(v.w);
  ((ushort4*)out)[i] = o;
}

// ---------------- MFMA GEMM: C[M x 128] (bf16) = A[M x 128] @ Bt^T (+ rs*u + v) ----------------
// Optional fused attention dots (shfl-reduced; 4 LDS atomics per (i,r) per wave):
// alsO/aldO get (x . asv), (x . adv) per row into .x (layer 0) or .y (layer 1).
template<bool AF32>
__global__ __launch_bounds__(256) void k_gemm(const void* __restrict__ Ap, const ushort* __restrict__ Bt,
                                              ushort* __restrict__ C, long M, int ostride, int ooff,
                                              const float* __restrict__ u, const float* __restrict__ v,
                                              const float* __restrict__ rs,
                                              const float* __restrict__ asv, const float* __restrict__ adv,
                                              float2* __restrict__ alsO, float2* __restrict__ aldO, int layer){
  __shared__ ushort As[128*128];
  __shared__ ushort Bs[128*128];
  __shared__ float sAls[128], sAld[128];
  int tid = threadIdx.x;
  long m0 = (long)blockIdx.x * 128;
  if (asv && tid < 128){ sAls[tid] = 0.f; sAld[tid] = 0.f; }
  {
    const int4* Bg = (const int4*)Bt;
#pragma unroll
    for (int it=0; it<8; ++it){
      int chunk = tid + it*256;
      int row = chunk >> 4, c = chunk & 15;
      int4 vv = Bg[chunk];
      *(int4*)&Bs[(row<<7) + (((c ^ row) & 15)<<3)] = vv;
    }
  }
  if (AF32){
    const float4* Ag = (const float4*)Ap;
#pragma unroll
    for (int it=0; it<16; ++it){
      int chunk = tid + it*256;
      int row = chunk >> 5, q = chunk & 31;
      long grow = m0 + row;
      float4 vv = make_float4(0.f,0.f,0.f,0.f);
      if (grow < M) vv = Ag[grow*32 + q];
      ushort4 h; h.x=f2b(vv.x); h.y=f2b(vv.y); h.z=f2b(vv.z); h.w=f2b(vv.w);
      int c16 = q >> 1, half = q & 1;
      *(ushort4*)&As[(row<<7) + (((c16 ^ row)&15)<<3) + (half<<2)] = h;
    }
  } else {
    const int4* Ag = (const int4*)Ap;
#pragma unroll
    for (int it=0; it<8; ++it){
      int chunk = tid + it*256;
      int row = chunk >> 4, c = chunk & 15;
      long grow = m0 + row;
      int4 vv = make_int4(0,0,0,0);
      if (grow < M) vv = Ag[grow*16 + c];
      *(int4*)&As[(row<<7) + (((c ^ row)&15)<<3)] = vv;
    }
  }
  __syncthreads();
  int wave = tid >> 6, lane = tid & 63;
  int wm = (wave & 1) << 6, wn = (wave >> 1) << 6;
  int l15 = lane & 15, quad = lane >> 4;
  f32x4 acc[4][4] = {};
#pragma unroll
  for (int kk=0; kk<4; ++kk){
    int ch = (kk<<2) + quad;
    short8 a[4], b[4];
#pragma unroll
    for (int i=0;i<4;++i){ int r = wm + (i<<4) + l15; a[i] = *(const short8*)&As[(r<<7) + (((ch ^ r)&15)<<3)]; }
#pragma unroll
    for (int j=0;j<4;++j){ int r = wn + (j<<4) + l15; b[j] = *(const short8*)&Bs[(r<<7) + (((ch ^ r)&15)<<3)]; }
#pragma unroll
    for (int i=0;i<4;++i)
#pragma unroll
      for (int j=0;j<4;++j)
        acc[i][j] = __builtin_amdgcn_mfma_f32_16x16x32_bf16(a[i], b[j], acc[i][j], 0,0,0);
  }
#pragma unroll
  for (int i=0;i<4;++i){
#pragma unroll
    for (int r=0;r<4;++r){
      int lrow = wm + (i<<4) + (quad<<2) + r;
      long grow = m0 + lrow;
      float pAls = 0.f, pAld = 0.f;
      if (grow < M){
        float rsv = rs ? rs[grow] : 0.f;
#pragma unroll
        for (int j=0;j<4;++j){
          int col = wn + (j<<4) + l15;
          float x = acc[i][j][r];
          if (u) x += rsv*u[col] + v[col];
          if (asv){ pAls += x*asv[col]; pAld += x*adv[col]; }
          C[grow*(long)ostride + ooff + col] = f2b(x);
        }
      }
      if (asv){
        // reduce across the 16 l15 lanes of this quad (offsets stay within quad group)
#pragma unroll
        for (int o=8;o>0;o>>=1){ pAls += __shfl_xor(pAls,o); pAld += __shfl_xor(pAld,o); }
        if (l15 == 0 && grow < M){ atomicAdd(&sAls[lrow], pAls); atomicAdd(&sAld[lrow], pAld); }
      }
    }
  }
  if (asv){
    __syncthreads();
    if (tid < 128){
      long grow = m0 + tid;
      if (grow < M){
        if (layer == 0){ alsO[grow].x = sAls[tid]; aldO[grow].x = sAld[tid]; }
        else           { alsO[grow].y = sAls[tid]; aldO[grow].y = sAld[tid]; }
      }
    }
  }
}

// ---------------- gather / aggregation ----------------

__global__ void k_gather(const int* __restrict__ trip, const float* __restrict__ attP,
                         const ushort* __restrict__ valP, ushort* __restrict__ h0, long T, long NEnt){
  int w = threadIdx.x >> 6, lane = threadIdx.x & 63;
  long t = (long)blockIdx.x*4 + w;
  if (t >= T) return;
  int a = trip[3*t+2], v = trip[3*t+1];
  float2 ap = ((const float2*)(attP + (long)a*128))[lane];
  unsigned vp = ((const unsigned*)(valP + (long)v*128))[lane];
  ushort2 o;
  o.x = f2b(ap.x + b2f((ushort)(vp & 0xffff)));
  o.y = f2b(ap.y + b2f((ushort)(vp >> 16)));
  ((ushort2*)(h0 + (NEnt + t)*128))[lane] = o;
}

// out[d] = dinv[d]^2*h[d] + sum_e dinv[s]*dinv[d]*h[s]   (bf16 out; optional rowsum rs)
// fully padded 4-wide pipelined gather: no serial remainder; padded slots reuse
// the last valid edge's row (L2-hot) with weight forced to 0 (exact).
__global__ void k_agg(const int* __restrict__ rp, const int2* __restrict__ pk,
                      const ushort* __restrict__ h, const float* __restrict__ dinv,
                      ushort* __restrict__ outH, float* __restrict__ rs, long R){
  int w = threadIdx.x>>6, lane = threadIdx.x&63;
  long d = (long)blockIdx.x*4 + w;
  if (d >= R) return;
  int r0 = rp[d], r1 = rp[d+1], ne = r1 - r0;
  float dv = dinv[d];
  unsigned hv = ((const unsigned*)(h + d*128))[lane];
  // batch edge meta (one edge per lane)
  float wE = 0.f; int srcc = 0;
  if (lane < ne){ int2 p = pk[r0 + lane]; srcc = p.x; wE = dv * __int_as_float(p.y); }
  float wself = dv*dv;
  float ax = wself*b2f((ushort)(hv&0xffff));
  float ay = wself*b2f((ushort)(hv>>16));
  float wsum = wself;
  int lim = ne < 64 ? ne : 64;
  for (int j = 0; j < lim; j += 4){
    int i1 = (j+1<lim)? j+1 : lim-1;
    int i2 = (j+2<lim)? j+2 : lim-1;
    int i3 = (j+3<lim)? j+3 : lim-1;
    float w0=__shfl(wE,j),   w1=__shfl(wE,i1),   w2=__shfl(wE,i2),   w3=__shfl(wE,i3);
    int   s0=__shfl(srcc,j), s1=__shfl(srcc,i1), s2=__shfl(srcc,i2), s3=__shfl(srcc,i3);
    if (j+1>=lim) w1 = 0.f;
    if (j+2>=lim) w2 = 0.f;
    if (j+3>=lim) w3 = 0.f;
    unsigned v0 = ((const unsigned*)(h + (long)s0*128))[lane];
    unsigned v1 = ((const unsigned*)(h + (long)s1*128))[lane];
    unsigned v2 = ((const unsigned*)(h + (long)s2*128))[lane];
    unsigned v3 = ((const unsigned*)(h + (long)s3*128))[lane];
    wsum += w0+w1+w2+w3;
    ax += w0*b2f((ushort)(v0&0xffff)) + w1*b2f((ushort)(v1&0xffff))
        + w2*b2f((ushort)(v2&0xffff)) + w3*b2f((ushort)(v3&0xffff));
    ay += w0*b2f((ushort)(v0>>16)) + w1*b2f((ushort)(v1>>16))
        + w2*b2f((ushort)(v2>>16)) + w3*b2f((ushort)(v3>>16));
  }
  for (int e = r0+64; e < r1; ++e){   // rare deg>64
    int2 p = pk[e];
    float wgt = dv * __int_as_float(p.y);
    unsigned sv = ((const unsigned*)(h + (long)p.x*128))[lane];
    ax += wgt * b2f((ushort)(sv&0xffff));
    ay += wgt * b2f((ushort)(sv>>16));
    wsum += wgt;
  }
  ushort2 o; o.x = f2b(ax); o.y = f2b(ay);
  ((ushort2*)(outH + d*128))[lane] = o;
  if (rs && lane==0) rs[d] = wsum;
}

// Fused dual-layer GAT via CSR gather over interleaved hgI; writes final out (+b1+b2+ent_feats)
// batch0 accumulate loop: padded 4-wide pipelined (no serial remainder).
__global__ void k_gat_csr(const int* __restrict__ rp, const int2* __restrict__ pk,
      const uint2* __restrict__ hgI,
      const float2* __restrict__ alsP, const float2* __restrict__ aldP,
      const float* __restrict__ loopA, const float* __restrict__ csc,
      const float* __restrict__ b1, const float* __restrict__ b2v,
      const float* __restrict__ entf, float* __restrict__ out, long R){
  int w = threadIdx.x>>6, lane = threadIdx.x&63;
  long d = (long)blockIdx.x*4 + w;
  if (d >= R) return;
  int r0 = rp[d], r1 = rp[d+1], ne = r1 - r0;
  float c1 = csc[0], c2 = csc[1];
  float2 aldd = aldP[d];
  float2 alsd = alsP[d];
  float la = loopA[d];
  float a1s = lrelu(alsd.x + aldd.x + c1*la);
  float a2s = lrelu(alsd.y + aldd.y + c2*la);
  // batch0 edge alphas, cached in registers
  float a1c = -1e30f, a2c = -1e30f; int srcc = 0;
  if (lane < ne){
    int2 p = pk[r0+lane];
    float lab = __int_as_float(p.y);
    float2 av = alsP[p.x];
    a1c = lrelu(av.x + aldd.x + c1*lab);
    a2c = lrelu(av.y + aldd.y + c2*lab);
    srcc = p.x;
  }
  float m1 = a1c, m2 = a2c;
  for (int o=32;o>0;o>>=1){ m1 = fmaxf(m1,__shfl_down(m1,o)); m2 = fmaxf(m2,__shfl_down(m2,o)); }
  m1 = fmaxf(__shfl(m1,0), a1s); m2 = fmaxf(__shfl(m2,0), a2s);
  for (int base=64; base<ne; base+=64){   // rare (deg>64)
    int i = base+lane; float x1=-1e30f, x2=-1e30f;
    if (i<ne){ int2 p = pk[r0+i]; float lab = __int_as_float(p.y); float2 av = alsP[p.x];
      x1 = lrelu(av.x + aldd.x + c1*lab); x2 = lrelu(av.y + aldd.y + c2*lab); }
    for (int o=32;o>0;o>>=1){ x1 = fmaxf(x1,__shfl_down(x1,o)); x2 = fmaxf(x2,__shfl_down(x2,o)); }
    m1 = fmaxf(m1, __shfl(x1,0)); m2 = fmaxf(m2, __shfl(x2,0));
  }
  float e1s = __expf(a1s-m1), e2s = __expf(a2s-m2);
  float z1 = e1s, z2 = e2s;
  bool lo = lane < 32;
  uint2 hv = hgI[d*64 + lane];
  float ws0 = lo ? e1s : e2s;
  float ac0 = ws0*b2f((ushort)(hv.x&0xffff));
  float ac1 = ws0*b2f((ushort)(hv.x>>16));
  float ac2 = ws0*b2f((ushort)(hv.y&0xffff));
  float ac3 = ws0*b2f((ushort)(hv.y>>16));
  {
    float e1 = (lane<ne) ? __expf(a1c-m1) : 0.f;
    float e2 = (lane<ne) ? __expf(a2c-m2) : 0.f;
    int lim = ne < 64 ? ne : 64;
    for (int j = 0; j < lim; j += 4){
      int i1 = (j+1<lim)? j+1 : lim-1;
      int i2 = (j+2<lim)? j+2 : lim-1;
      int i3 = (j+3<lim)? j+3 : lim-1;
      float f1a=__shfl(e1,j),   f1b=__shfl(e1,i1),  f1c=__shfl(e1,i2),  f1d=__shfl(e1,i3);
      float f2a=__shfl(e2,j),   f2bb=__shfl(e2,i1), f2c=__shfl(e2,i2),  f2d=__shfl(e2,i3);
      int   sa=__shfl(srcc,j),  sb=__shfl(srcc,i1), sc=__shfl(srcc,i2), sd=__shfl(srcc,i3);
      if (j+1>=lim){ f1b = 0.f; f2bb = 0.f; }
      if (j+2>=lim){ f1c = 0.f; f2c = 0.f; }
      if (j+3>=lim){ f1d = 0.f; f2d = 0.f; }
      uint2 va = hgI[(long)sa*64 + lane];
      uint2 vb = hgI[(long)sb*64 + lane];
      uint2 vc = hgI[(long)sc*64 + lane];
      uint2 vd = hgI[(long)sd*64 + lane];
      z1 += f1a+f1b+f1c+f1d; z2 += f2a+f2bb+f2c+f2d;
      float fa = lo ? f1a : f2a, fb = lo ? f1b : f2bb, fc = lo ? f1c : f2c, fd = lo ? f1d : f2d;
      ac0 += fa*b2f((ushort)(va.x&0xffff)) + fb*b2f((ushort)(vb.x&0xffff))
           + fc*b2f((ushort)(vc.x&0xffff)) + fd*b2f((ushort)(vd.x&0xffff));
      ac1 += fa*b2f((ushort)(va.x>>16)) + fb*b2f((ushort)(vb.x>>16))
           + fc*b2f((ushort)(vc.x>>16)) + fd*b2f((ushort)(vd.x>>16));
      ac2 += fa*b2f((ushort)(va.y&0xffff)) + fb*b2f((ushort)(vb.y&0xffff))
           + fc*b2f((ushort)(vc.y&0xffff)) + fd*b2f((ushort)(vd.y&0xffff));
      ac3 += fa*b2f((ushort)(va.y>>16)) + fb*b2f((ushort)(vb.y>>16))
           + fc*b2f((ushort)(vc.y>>16)) + fd*b2f((ushort)(vd.y>>16));
    }
  }
  for (int base=64; base<ne; base+=64){   // rare
    int i = base+lane; float e1=0.f, e2=0.f; int src = 0;
    if (i<ne){ int2 p = pk[r0+i]; float lab = __int_as_float(p.y); float2 av = alsP[p.x];
      e1 = __expf(lrelu(av.x + aldd.x + c1*lab)-m1);
      e2 = __expf(lrelu(av.y + aldd.y + c2*lab)-m2);
      src = p.x; }
    int lim2 = (ne-base < 64) ? (ne-base) : 64;
    for (int j2=0;j2<lim2;++j2){
      float f1 = __shfl(e1,j2), f2 = __shfl(e2,j2); int sj = __shfl(src,j2);
      z1 += f1; z2 += f2;
      uint2 vv = hgI[(long)sj*64 + lane];
      float f = lo ? f1 : f2;
      ac0 += f*b2f((ushort)(vv.x&0xffff));
      ac1 += f*b2f((ushort)(vv.x>>16));
      ac2 += f*b2f((ushort)(vv.y&0xffff));
      ac3 += f*b2f((ushort)(vv.y>>16));
    }
  }
  float iz = lo ? 1.f/(z1+1e-16f) : 1.f/(z2+1e-16f);
  ac0 *= iz; ac1 *= iz; ac2 *= iz; ac3 *= iz;
  int pl = lane ^ 32;
  float p0 = __shfl(ac0, pl), p1 = __shfl(ac1, pl), p2 = __shfl(ac2, pl), p3 = __shfl(ac3, pl);
  if (lo){
    float4 bb1 = ((const float4*)b1)[lane];
    float4 bb2 = ((const float4*)b2v)[lane];
    float4 ef  = ((const float4*)(entf + d*128))[lane];
    float4 o;
    o.x = ac0 + p0 + bb1.x + bb2.x + ef.x;
    o.y = ac1 + p1 + bb1.y + bb2.y + ef.y;
    o.z = ac2 + p2 + bb1.z + bb2.z + ef.z;
    o.w = ac3 + p3 + bb1.w + bb2.w + ef.w;
    ((float4*)(out + d*128))[lane] = o;
  }
}

// ---------------- host ----------------

extern "C" void kernel_launch(void* const* d_in, const int* in_sizes, int n_in,
                              void* d_out, int out_size, void* d_ws, size_t ws_size,
                              hipStream_t stream) {
  const int*   trip = (const int*)d_in[0];
  const int*   ee   = (const int*)d_in[1];
  const float* eel  = (const float*)d_in[2];
  const int*   ve   = (const int*)d_in[3];
  const float* att  = (const float*)d_in[5];
  const float* valf = (const float*)d_in[6];
  const float* entf = (const float*)d_in[7];
  const float* W    = (const float*)d_in[8];
  const float* G1   = (const float*)d_in[9];
  const float* g1b  = (const float*)d_in[10];
  const float* G2   = (const float*)d_in[11];
  const float* g2b  = (const float*)d_in[12];
  const float* Wl1  = (const float*)d_in[13];
  const float* as1v = (const float*)d_in[14];
  const float* ad1v = (const float*)d_in[15];
  const float* We1  = (const float*)d_in[16];
  const float* ae1  = (const float*)d_in[17];
  const float* b1   = (const float*)d_in[18];
  const float* Wl2  = (const float*)d_in[19];
  const float* as2v = (const float*)d_in[20];
  const float* ad2v = (const float*)d_in[21];
  const float* We2  = (const float*)d_in[22];
  const float* ae2  = (const float*)d_in[23];
  const float* b2   = (const float*)d_in[24];

  long T    = in_sizes[0]/3;
  long E1   = in_sizes[1]/2;
  long E2   = in_sizes[3]/2;
  long NA   = in_sizes[5]/128;
  long NV   = in_sizes[6]/128;
  long NEnt = in_sizes[7]/128;
  long N    = NEnt + T;

  size_t off = 0;
  auto alloc = [&](size_t bytes)->char*{
    char* p = (char*)d_ws + off; off = (off + bytes + 255) & ~(size_t)255; return p;
  };
  ushort* nodes0 = (ushort*)alloc((size_t)N*128*2);   // later reused as hgI (NEnt*256 ushorts)
  ushort* y1     = (ushort*)alloc((size_t)N*128*2);   // valP overlays this before y1 is written
  ushort* y2     = (ushort*)alloc((size_t)NEnt*128*2);
  float*  attP   = (float*)alloc((size_t)NA*128*4);
  int*    degi   = (int*)alloc(N*4);
  float*  dinv   = (float*)alloc(N*4);
  int*    cntE   = (int*)alloc(NEnt*4);
  float*  loopS  = (float*)alloc(NEnt*4);
  float*  loopA  = (float*)alloc(NEnt*4);
  float2* alsP   = (float2*)alloc(NEnt*8);
  float2* aldP   = (float2*)alloc(NEnt*8);
  float*  rs     = (float*)alloc(NEnt*4);
  int*    rpV    = (int*)alloc((N+1)*4);
  int*    curV   = (int*)alloc(N*4);
  int2*   pkV    = (int2*)alloc((size_t)E2*8);
  int*    rpE    = (int*)alloc((NEnt+1)*4);
  int*    curE   = (int*)alloc(NEnt*4);
  int2*   pkE    = (int2*)alloc((size_t)E1*8);
  int*    bsumV  = (int*)alloc(512*4);
  int*    boffV  = (int*)alloc(512*4);
  int*    bsumE  = (int*)alloc(512*4);
  int*    boffE  = (int*)alloc(512*4);
  ushort* Wvt    = (ushort*)alloc(16384*2);
  float*  P      = (float*)alloc(16384*4);
  ushort* M1t    = (ushort*)alloc(16384*2);
  ushort* M2t    = (ushort*)alloc(16384*2);
  float*  u1     = (float*)alloc(128*4);
  float*  v1     = (float*)alloc(128*4);
  float*  u2     = (float*)alloc(128*4);
  float*  v2     = (float*)alloc(128*4);
  float*  csc    = (float*)alloc(256);

  ushort* valP = y1;                 // dead before y1 is written
  ushort* hgI  = nodes0;             // dead after y1 aggregation

  auto cdiv = [](long a, long b)->int{ return (int)((a + b - 1)/b); };
  int nbV = cdiv(N, 1024), nbE = cdiv(NEnt, 1024);

  // degrees / loop_attr
  k_zero<<<cdiv(N,256),256,0,stream>>>(degi, N, cntE, loopS, NEnt);
  k_deg_val<<<cdiv(E2,256),256,0,stream>>>(ve, E2, degi);
  k_deg_ent<<<cdiv(E1,256),256,0,stream>>>(ee, eel, E1, cntE, loopS);
  k_dinv<<<cdiv(N,256),256,0,stream>>>(degi, dinv, N, cntE, loopS, loopA, NEnt);

  // CSR build
  k_scan1<<<nbV,256,0,stream>>>(degi, N, rpV, bsumV);
  k_scan2<<<1,512,0,stream>>>(bsumV, boffV, nbV);
  k_scan3<<<cdiv(N+1,256),256,0,stream>>>(rpV, curV, boffV, N, (int)E2);
  k_scan1<<<nbE,256,0,stream>>>(cntE, NEnt, rpE, bsumE);
  k_scan2<<<1,512,0,stream>>>(bsumE, boffE, nbE);
  k_scan3<<<cdiv(NEnt+1,256),256,0,stream>>>(rpE, curE, boffE, NEnt, (int)E1);
  k_scatter_val<<<cdiv(E2,256),256,0,stream>>>(ve, E2, dinv, curV, pkV);
  k_scatter_ent<<<cdiv(E1,256),256,0,stream>>>(ee, eel, E1, curE, pkE);

  // tiny weight chains: P=G1@G2, M_k = P@Wl_k (bf16,T), u_k=(g1b@G2)@Wl_k, v_k=g2b@Wl_k
  k_wvt<<<64,256,0,stream>>>(W, Wvt);
  k_mm128<<<64,256,0,stream>>>(G1, G2, P);
  k_mmt<<<64,256,0,stream>>>(P, Wl1, M1t);
  k_mmt<<<64,256,0,stream>>>(P, Wl2, M2t);
  k_uv<<<1,128,0,stream>>>(g1b, g2b, G2, Wl1, Wl2, u1, v1, u2, v2);
  k_csc<<<1,128,0,stream>>>(We1, ae1, We2, ae2, csc);
  k_attP<<<cdiv(NA*128,256),256,0,stream>>>(att, W, attP, NA);

  // nodes0 (bf16): ent rows = ent_feats; val rows = attP[a] + (valf@Wv)[v]
  k_gemm<true><<<cdiv(NV,128),256,0,stream>>>(valf, Wvt, valP, NV, 128, 0, nullptr, nullptr, nullptr,
                                              nullptr, nullptr, nullptr, nullptr, 0);
  k_cast<<<cdiv(NEnt*32,256),256,0,stream>>>(entf, nodes0, NEnt*32);
  k_gather<<<cdiv(T,4),256,0,stream>>>(trip, attP, valP, nodes0, T, NEnt);

  // y1 = A(nodes0) over all N ; y2 = A(y1) over NEnt rows (+rowsum rs)
  k_agg<<<cdiv(N,4),256,0,stream>>>(rpV, pkV, nodes0, dinv, y1, nullptr, N);
  k_agg<<<cdiv(NEnt,4),256,0,stream>>>(rpV, pkV, y1, dinv, y2, rs, NEnt);

  // hgI rows = [ y2@M1 + rs*u1 + v1 | y2@M2 + rs*u2 + v2 ]; attention dots fused into epilogue
  k_gemm<false><<<cdiv(NEnt,128),256,0,stream>>>(y2, M1t, (ushort*)hgI, NEnt, 256, 0,   u1, v1, rs,
                                                 as1v, ad1v, alsP, aldP, 0);
  k_gemm<false><<<cdiv(NEnt,128),256,0,stream>>>(y2, M2t, (ushort*)hgI, NEnt, 256, 128, u2, v2, rs,
                                                 as2v, ad2v, alsP, aldP, 1);

  // fused dual-layer GAT aggregation -> final output
  k_gat_csr<<<cdiv(NEnt,4),256,0,stream>>>(rpE, pkE, (const uint2*)hgI, alsP, aldP,
                                           loopA, csc, b1, b2, entf, (float*)d_out, NEnt);
}

// Round 11
// 941.871 us; speedup vs baseline: 1.1462x; 1.1377x over previous
//
#include <hip/hip_runtime.h>
#include <hip/hip_bf16.h>

typedef __attribute__((ext_vector_type(8))) short short8;
typedef __attribute__((ext_vector_type(4))) float f32x4;

__device__ __forceinline__ float b2f(ushort u){ unsigned v = ((unsigned)u)<<16; float f; __builtin_memcpy(&f,&v,4); return f; }
__device__ __forceinline__ ushort f2b(float x){ __hip_bfloat16 h = __float2bfloat16(x); ushort u; __builtin_memcpy(&u,&h,2); return u; }
__device__ __forceinline__ float lrelu(float x){ return x >= 0.f ? x : 0.2f*x; }

// ---------------- prep (fused launches; bodies identical to R8) ----------------

__global__ void k_zero(int* degi, long N, int* cntE, float* loopS, long NE){
  long i = (long)blockIdx.x*256 + threadIdx.x;
  if (i < N) degi[i] = 0;
  if (i < NE) { cntE[i] = 0; loopS[i] = 0.f; }
}

// deg_val + deg_ent fused (independent counters)
__global__ void k_deg(const int* __restrict__ ve, long E2, int* degi,
                      const int* __restrict__ ee, const float* __restrict__ lab, long E1,
                      int* cntE, float* loopS){
  long e = (long)blockIdx.x*256 + threadIdx.x;
  if (e < E2) atomicAdd(&degi[ve[2*e+1]], 1);
  if (e < E1){ int d = ee[2*e+1]; atomicAdd(&cntE[d],1); atomicAdd(&loopS[d], lab[e]); }
}

__global__ void k_dinv(const int* degi, float* dinv, long N, const int* cntE, const float* loopS, float* loopA, long NE){
  long n = (long)blockIdx.x*256 + threadIdx.x;
  if (n < N) dinv[n] = rsqrtf((float)(degi[n]+1));
  if (n < NE) loopA[n] = loopS[n] / fmaxf((float)cntE[n], 1.f);
}

// scan stage 1 for both CSRs in one launch (block-range partition)
__global__ void k_scan1_2(const int* __restrict__ degV, long Lv, int* __restrict__ psV, int* __restrict__ bsumV, int nbV,
                          const int* __restrict__ degE, long Le, int* __restrict__ psE, int* __restrict__ bsumE){
  __shared__ int s[256];
  const int* deg; long L; int* ps; int* bsum; long bid;
  if ((int)blockIdx.x < nbV){ deg=degV; L=Lv; ps=psV; bsum=bsumV; bid=blockIdx.x; }
  else                      { deg=degE; L=Le; ps=psE; bsum=bsumE; bid=(long)blockIdx.x-nbV; }
  long base = bid*1024;
  int t = threadIdx.x;
  int v[4]; int sum = 0;
#pragma unroll
  for (int i=0;i<4;++i){ long idx = base + t*4 + i; v[i] = (idx<L) ? deg[idx] : 0; sum += v[i]; }
  s[t] = sum; __syncthreads();
  for (int off=1; off<256; off<<=1){
    int x = 0;
    if (t>=off) x = s[t-off];
    __syncthreads();
    if (t>=off) s[t] += x;
    __syncthreads();
  }
  int run = s[t] - sum;
#pragma unroll
  for (int i=0;i<4;++i){ long idx = base + t*4 + i; if (idx<L) ps[idx] = run; run += v[i]; }
  if (t==255) bsum[bid] = s[255];
}

// scan stage 2 for both CSRs (block 0 = V, block 1 = E)
__global__ void k_scan2_2(const int* __restrict__ bsumV, int* __restrict__ boffV, int nbV,
                          const int* __restrict__ bsumE, int* __restrict__ boffE, int nbE){
  __shared__ int s[512];
  const int* bsum = (blockIdx.x==0) ? bsumV : bsumE;
  int* boff       = (blockIdx.x==0) ? boffV : boffE;
  int nb          = (blockIdx.x==0) ? nbV   : nbE;
  int t = threadIdx.x;
  int v = (t<nb) ? bsum[t] : 0;
  s[t] = v; __syncthreads();
  for (int off=1; off<512; off<<=1){
    int x = 0;
    if (t>=off) x = s[t-off];
    __syncthreads();
    if (t>=off) s[t] += x;
    __syncthreads();
  }
  if (t<nb) boff[t] = s[t] - v;
}

// scan stage 3 for both CSRs
__global__ void k_scan3_2(int* __restrict__ psV, int* __restrict__ curV, const int* __restrict__ boffV, long Lv, int Ev, int nb3V,
                          int* __restrict__ psE, int* __restrict__ curE, const int* __restrict__ boffE, long Le, int Ee){
  long bid = blockIdx.x; int* ps; int* cur; const int* boff; long L; int E;
  if (bid < nb3V){ ps=psV; cur=curV; boff=boffV; L=Lv; E=Ev; }
  else { bid -= nb3V; ps=psE; cur=curE; boff=boffE; L=Le; E=Ee; }
  long i = bid*256 + threadIdx.x;
  if (i < L){ int v = ps[i] + boff[i>>10]; ps[i] = v; cur[i] = v; }
  if (i == L) ps[L] = E;
}

// both scatters fused
__global__ void k_scatter2(const int* __restrict__ ve, long E2, const float* __restrict__ dinv,
                           int* __restrict__ curV, int2* __restrict__ pkV,
                           const int* __restrict__ ee, const float* __restrict__ lab, long E1,
                           int* __restrict__ curE, int2* __restrict__ pkE){
  long e = (long)blockIdx.x*256 + threadIdx.x;
  if (e < E2){
    int s = ve[2*e], d = ve[2*e+1];
    int pos = atomicAdd(&curV[d], 1);
    int2 p; p.x = s; p.y = __float_as_int(dinv[s]);
    pkV[pos] = p;
  }
  if (e < E1){
    int s = ee[2*e], d = ee[2*e+1];
    int pos = atomicAdd(&curE[d], 1);
    int2 p; p.x = s; p.y = __float_as_int(lab[e]);
    pkE[pos] = p;
  }
}

// ---------------- tiny weight-chain prep, fused: wvt | mm128 | uv | csc | attP ----------------
__global__ void k_tiny1(const float* __restrict__ W, ushort* __restrict__ Wvt,
                        const float* __restrict__ G1, const float* __restrict__ G2, float* __restrict__ P,
                        const float* g1b, const float* g2b,
                        const float* __restrict__ Wl1, const float* __restrict__ Wl2,
                        float* u1, float* v1, float* u2, float* v2,
                        const float* We1, const float* ae1, const float* We2, const float* ae2, float* csc,
                        const float* __restrict__ att, float* __restrict__ attP, long NA){
  __shared__ float shA[128];
  __shared__ float shB[128];
  int bx = blockIdx.x, t = threadIdx.x;
  if (bx < 64){                       // wvt
    int o = bx*256 + t; int k = o>>7, n = o&127;
    Wvt[n*128+k] = f2b(W[(128+k)*128+n]);
  } else if (bx < 128){               // mm128: P = G1@G2
    int o = (bx-64)*256 + t; int k = o>>7, n = o&127;
    float s = 0.f;
    for (int j=0;j<128;++j) s += G1[k*128+j]*G2[j*128+n];
    P[o] = s;
  } else if (bx == 128){              // uv
    if (t < 128){
      float s = 0.f;
      for (int k=0;k<128;++k) s += g1b[k]*G2[k*128+t];
      shA[t] = s;
    }
    __syncthreads();
    if (t < 128){
      float a=0.f,b=0.f,c=0.f,dd=0.f;
      for (int j=0;j<128;++j){
        float w1 = Wl1[j*128+t], w2 = Wl2[j*128+t];
        a += shA[j]*w1; c += shA[j]*w2; b += g2b[j]*w1; dd += g2b[j]*w2;
      }
      u1[t]=a; v1[t]=b; u2[t]=c; v2[t]=dd;
    }
  } else if (bx == 129){              // csc
    if (t < 128){ shA[t] = We1[t]*ae1[t]; shB[t] = We2[t]*ae2[t]; }
    __syncthreads();
    for (int off=64; off>0; off>>=1){
      if (t<off){ shA[t]+=shA[t+off]; shB[t]+=shB[t+off]; }
      __syncthreads();
    }
    if (t==0){ csc[0]=shA[0]; csc[1]=shB[0]; }
  } else {                            // attP
    long o = (long)(bx-130)*256 + t;
    if (o < NA*128){
      long a = o>>7; int n = o&127;
      float s = 0.f;
      for (int j=0;j<128;++j) s += att[a*128+j]*W[j*128+n];
      attP[o] = s;
    }
  }
}

// both Mt matrices in one launch
__global__ void k_mmt2(const float* __restrict__ P, const float* __restrict__ Wl1, const float* __restrict__ Wl2,
                       ushort* __restrict__ M1t, ushort* __restrict__ M2t){
  int bx = blockIdx.x;
  const float* Wl = (bx < 64) ? Wl1 : Wl2;
  ushort* Mt      = (bx < 64) ? M1t : M2t;
  int o = (bx & 63)*256 + threadIdx.x; int k = o>>7, n = o&127;
  float s = 0.f;
  for (int j=0;j<128;++j) s += P[k*128+j]*Wl[j*128+n];
  Mt[n*128+k] = f2b(s);
}

// ---------------- MFMA GEMM (R8 form): C[M x 128] (bf16) = A[M x 128] @ Bt^T (+ rs*u + v) ----------------
template<bool AF32>
__global__ __launch_bounds__(256) void k_gemm(const void* __restrict__ Ap, const ushort* __restrict__ Bt,
                                              ushort* __restrict__ C, long M, int ostride, int ooff,
                                              const float* __restrict__ u, const float* __restrict__ v,
                                              const float* __restrict__ rs){
  __shared__ ushort As[128*128];
  __shared__ ushort Bs[128*128];
  int tid = threadIdx.x;
  long m0 = (long)blockIdx.x * 128;
  {
    const int4* Bg = (const int4*)Bt;
#pragma unroll
    for (int it=0; it<8; ++it){
      int chunk = tid + it*256;
      int row = chunk >> 4, c = chunk & 15;
      int4 vv = Bg[chunk];
      *(int4*)&Bs[(row<<7) + (((c ^ row) & 15)<<3)] = vv;
    }
  }
  if (AF32){
    const float4* Ag = (const float4*)Ap;
#pragma unroll
    for (int it=0; it<16; ++it){
      int chunk = tid + it*256;
      int row = chunk >> 5, q = chunk & 31;
      long grow = m0 + row;
      float4 vv = make_float4(0.f,0.f,0.f,0.f);
      if (grow < M) vv = Ag[grow*32 + q];
      ushort4 h; h.x=f2b(vv.x); h.y=f2b(vv.y); h.z=f2b(vv.z); h.w=f2b(vv.w);
      int c16 = q >> 1, half = q & 1;
      *(ushort4*)&As[(row<<7) + (((c16 ^ row)&15)<<3) + (half<<2)] = h;
    }
  } else {
    const int4* Ag = (const int4*)Ap;
#pragma unroll
    for (int it=0; it<8; ++it){
      int chunk = tid + it*256;
      int row = chunk >> 4, c = chunk & 15;
      long grow = m0 + row;
      int4 vv = make_int4(0,0,0,0);
      if (grow < M) vv = Ag[grow*16 + c];
      *(int4*)&As[(row<<7) + (((c ^ row)&15)<<3)] = vv;
    }
  }
  __syncthreads();
  int wave = tid >> 6, lane = tid & 63;
  int wm = (wave & 1) << 6, wn = (wave >> 1) << 6;
  int l15 = lane & 15, quad = lane >> 4;
  f32x4 acc[4][4] = {};
#pragma unroll
  for (int kk=0; kk<4; ++kk){
    int ch = (kk<<2) + quad;
    short8 a[4], b[4];
#pragma unroll
    for (int i=0;i<4;++i){ int r = wm + (i<<4) + l15; a[i] = *(const short8*)&As[(r<<7) + (((ch ^ r)&15)<<3)]; }
#pragma unroll
    for (int j=0;j<4;++j){ int r = wn + (j<<4) + l15; b[j] = *(const short8*)&Bs[(r<<7) + (((ch ^ r)&15)<<3)]; }
#pragma unroll
    for (int i=0;i<4;++i)
#pragma unroll
      for (int j=0;j<4;++j)
        acc[i][j] = __builtin_amdgcn_mfma_f32_16x16x32_bf16(a[i], b[j], acc[i][j], 0,0,0);
  }
#pragma unroll
  for (int i=0;i<4;++i){
#pragma unroll
    for (int r=0;r<4;++r){
      long grow = m0 + wm + (i<<4) + (quad<<2) + r;
      if (grow < M){
        float rsv = rs ? rs[grow] : 0.f;
#pragma unroll
        for (int j=0;j<4;++j){
          int col = wn + (j<<4) + l15;
          float x = acc[i][j][r];
          if (u) x += rsv*u[col] + v[col];
          C[grow*(long)ostride + ooff + col] = f2b(x);
        }
      }
    }
  }
}

// dual-layer hgI GEMM: both M1t/M2t products in one launch (block-range partition)
__global__ __launch_bounds__(256) void k_gemm2(const ushort* __restrict__ A,
                                               const ushort* __restrict__ Bt0, const ushort* __restrict__ Bt1,
                                               ushort* __restrict__ C, long M, int nb,
                                               const float* __restrict__ u0, const float* __restrict__ v0,
                                               const float* __restrict__ u1, const float* __restrict__ v1,
                                               const float* __restrict__ rs){
  __shared__ ushort As[128*128];
  __shared__ ushort Bs[128*128];
  int tid = threadIdx.x;
  int which = ((int)blockIdx.x >= nb) ? 1 : 0;
  const ushort* Bt = which ? Bt1 : Bt0;
  const float* u = which ? u1 : u0;
  const float* v = which ? v1 : v0;
  int ooff = which ? 128 : 0;
  long m0 = (long)((int)blockIdx.x - (which ? nb : 0)) * 128;
  {
    const int4* Bg = (const int4*)Bt;
#pragma unroll
    for (int it=0; it<8; ++it){
      int chunk = tid + it*256;
      int row = chunk >> 4, c = chunk & 15;
      int4 vv = Bg[chunk];
      *(int4*)&Bs[(row<<7) + (((c ^ row) & 15)<<3)] = vv;
    }
  }
  {
    const int4* Ag = (const int4*)A;
#pragma unroll
    for (int it=0; it<8; ++it){
      int chunk = tid + it*256;
      int row = chunk >> 4, c = chunk & 15;
      long grow = m0 + row;
      int4 vv = make_int4(0,0,0,0);
      if (grow < M) vv = Ag[grow*16 + c];
      *(int4*)&As[(row<<7) + (((c ^ row)&15)<<3)] = vv;
    }
  }
  __syncthreads();
  int wave = tid >> 6, lane = tid & 63;
  int wm = (wave & 1) << 6, wn = (wave >> 1) << 6;
  int l15 = lane & 15, quad = lane >> 4;
  f32x4 acc[4][4] = {};
#pragma unroll
  for (int kk=0; kk<4; ++kk){
    int ch = (kk<<2) + quad;
    short8 a[4], b[4];
#pragma unroll
    for (int i=0;i<4;++i){ int r = wm + (i<<4) + l15; a[i] = *(const short8*)&As[(r<<7) + (((ch ^ r)&15)<<3)]; }
#pragma unroll
    for (int j=0;j<4;++j){ int r = wn + (j<<4) + l15; b[j] = *(const short8*)&Bs[(r<<7) + (((ch ^ r)&15)<<3)]; }
#pragma unroll
    for (int i=0;i<4;++i)
#pragma unroll
      for (int j=0;j<4;++j)
        acc[i][j] = __builtin_amdgcn_mfma_f32_16x16x32_bf16(a[i], b[j], acc[i][j], 0,0,0);
  }
#pragma unroll
  for (int i=0;i<4;++i){
#pragma unroll
    for (int r=0;r<4;++r){
      long grow = m0 + wm + (i<<4) + (quad<<2) + r;
      if (grow < M){
        float rsv = rs[grow];
#pragma unroll
        for (int j=0;j<4;++j){
          int col = wn + (j<<4) + l15;
          float x = acc[i][j][r] + rsv*u[col] + v[col];
          C[grow*256L + ooff + col] = f2b(x);
        }
      }
    }
  }
}

// ---------------- gather / aggregation ----------------

// cast (ent rows) + gather (val rows) fused into one launch
__global__ void k_cast_gather(const float* __restrict__ entf, ushort* __restrict__ nodes0, long n4, int nbCast,
                              const int* __restrict__ trip, const float* __restrict__ attP,
                              const ushort* __restrict__ valP, long T, long NEnt){
  if ((int)blockIdx.x < nbCast){
    long i = (long)blockIdx.x*256 + threadIdx.x;
    if (i >= n4) return;
    float4 v = ((const float4*)entf)[i];
    ushort4 o; o.x=f2b(v.x); o.y=f2b(v.y); o.z=f2b(v.z); o.w=f2b(v.w);
    ((ushort4*)nodes0)[i] = o;
  } else {
    int w = threadIdx.x >> 6, lane = threadIdx.x & 63;
    long t = (long)((int)blockIdx.x - nbCast)*4 + w;
    if (t >= T) return;
    int a = trip[3*t+2], v = trip[3*t+1];
    float2 ap = ((const float2*)(attP + (long)a*128))[lane];
    unsigned vp = ((const unsigned*)(valP + (long)v*128))[lane];
    ushort2 o;
    o.x = f2b(ap.x + b2f((ushort)(vp & 0xffff)));
    o.y = f2b(ap.y + b2f((ushort)(vp >> 16)));
    ((ushort2*)(nodes0 + (NEnt + t)*128))[lane] = o;
  }
}

// out[d] = dinv[d]^2*h[d] + sum_e dinv[s]*dinv[d]*h[s]   (bf16 out; optional rowsum rs)
// fully padded 4-wide pipelined gather (R8 form)
__global__ void k_agg(const int* __restrict__ rp, const int2* __restrict__ pk,
                      const ushort* __restrict__ h, const float* __restrict__ dinv,
                      ushort* __restrict__ outH, float* __restrict__ rs, long R){
  int w = threadIdx.x>>6, lane = threadIdx.x&63;
  long d = (long)blockIdx.x*4 + w;
  if (d >= R) return;
  int r0 = rp[d], r1 = rp[d+1], ne = r1 - r0;
  float dv = dinv[d];
  unsigned hv = ((const unsigned*)(h + d*128))[lane];
  float wE = 0.f; int srcc = 0;
  if (lane < ne){ int2 p = pk[r0 + lane]; srcc = p.x; wE = dv * __int_as_float(p.y); }
  float wself = dv*dv;
  float ax = wself*b2f((ushort)(hv&0xffff));
  float ay = wself*b2f((ushort)(hv>>16));
  float wsum = wself;
  int lim = ne < 64 ? ne : 64;
  for (int j = 0; j < lim; j += 4){
    int i1 = (j+1<lim)? j+1 : lim-1;
    int i2 = (j+2<lim)? j+2 : lim-1;
    int i3 = (j+3<lim)? j+3 : lim-1;
    float w0=__shfl(wE,j),   w1=__shfl(wE,i1),   w2=__shfl(wE,i2),   w3=__shfl(wE,i3);
    int   s0=__shfl(srcc,j), s1=__shfl(srcc,i1), s2=__shfl(srcc,i2), s3=__shfl(srcc,i3);
    if (j+1>=lim) w1 = 0.f;
    if (j+2>=lim) w2 = 0.f;
    if (j+3>=lim) w3 = 0.f;
    unsigned v0 = ((const unsigned*)(h + (long)s0*128))[lane];
    unsigned v1 = ((const unsigned*)(h + (long)s1*128))[lane];
    unsigned v2 = ((const unsigned*)(h + (long)s2*128))[lane];
    unsigned v3 = ((const unsigned*)(h + (long)s3*128))[lane];
    wsum += w0+w1+w2+w3;
    ax += w0*b2f((ushort)(v0&0xffff)) + w1*b2f((ushort)(v1&0xffff))
        + w2*b2f((ushort)(v2&0xffff)) + w3*b2f((ushort)(v3&0xffff));
    ay += w0*b2f((ushort)(v0>>16)) + w1*b2f((ushort)(v1>>16))
        + w2*b2f((ushort)(v2>>16)) + w3*b2f((ushort)(v3>>16));
  }
  for (int e = r0+64; e < r1; ++e){   // rare deg>64
    int2 p = pk[e];
    float wgt = dv * __int_as_float(p.y);
    unsigned sv = ((const unsigned*)(h + (long)p.x*128))[lane];
    ax += wgt * b2f((ushort)(sv&0xffff));
    ay += wgt * b2f((ushort)(sv>>16));
    wsum += wgt;
  }
  ushort2 o; o.x = f2b(ax); o.y = f2b(ay);
  ((ushort2*)(outH + d*128))[lane] = o;
  if (rs && lane==0) rs[d] = wsum;
}

// per-node attention dots (R8 form)
__global__ void k_dots(const uint2* __restrict__ hgI,
                       const float* vs1, const float* vd1, const float* vs2, const float* vd2,
                       float2* __restrict__ alsP, float2* __restrict__ aldP, long R){
  int w = threadIdx.x>>6, lane = threadIdx.x&63;
  long n = (long)blockIdx.x*4 + w;
  if (n >= R) return;
  bool lo = lane < 32; int l = lo ? lane : lane-32;
  uint2 hv = hgI[n*64 + lane];
  float4 us = lo ? ((const float4*)vs1)[l] : ((const float4*)vs2)[l];
  float4 ud = lo ? ((const float4*)vd1)[l] : ((const float4*)vd2)[l];
  float h0 = b2f((ushort)(hv.x&0xffff)), h1 = b2f((ushort)(hv.x>>16));
  float h2 = b2f((ushort)(hv.y&0xffff)), h3 = b2f((ushort)(hv.y>>16));
  float ps = h0*us.x + h1*us.y + h2*us.z + h3*us.w;
  float pd = h0*ud.x + h1*ud.y + h2*ud.z + h3*ud.w;
  for (int o=16;o>0;o>>=1){ ps += __shfl_down(ps,o); pd += __shfl_down(pd,o); }
  if (lane==0) { alsP[n].x = ps; aldP[n].x = pd; }
  if (lane==32){ alsP[n].y = ps; aldP[n].y = pd; }
}

// Fused dual-layer GAT (R8 form: padded 4-wide pipelined batch0 loop)
__global__ void k_gat_csr(const int* __restrict__ rp, const int2* __restrict__ pk,
      const uint2* __restrict__ hgI,
      const float2* __restrict__ alsP, const float2* __restrict__ aldP,
      const float* __restrict__ loopA, const float* __restrict__ csc,
      const float* __restrict__ b1, const float* __restrict__ b2v,
      const float* __restrict__ entf, float* __restrict__ out, long R){
  int w = threadIdx.x>>6, lane = threadIdx.x&63;
  long d = (long)blockIdx.x*4 + w;
  if (d >= R) return;
  int r0 = rp[d], r1 = rp[d+1], ne = r1 - r0;
  float c1 = csc[0], c2 = csc[1];
  float2 aldd = aldP[d];
  float2 alsd = alsP[d];
  float la = loopA[d];
  float a1s = lrelu(alsd.x + aldd.x + c1*la);
  float a2s = lrelu(alsd.y + aldd.y + c2*la);
  float a1c = -1e30f, a2c = -1e30f; int srcc = 0;
  if (lane < ne){
    int2 p = pk[r0+lane];
    float lab = __int_as_float(p.y);
    float2 av = alsP[p.x];
    a1c = lrelu(av.x + aldd.x + c1*lab);
    a2c = lrelu(av.y + aldd.y + c2*lab);
    srcc = p.x;
  }
  float m1 = a1c, m2 = a2c;
  for (int o=32;o>0;o>>=1){ m1 = fmaxf(m1,__shfl_down(m1,o)); m2 = fmaxf(m2,__shfl_down(m2,o)); }
  m1 = fmaxf(__shfl(m1,0), a1s); m2 = fmaxf(__shfl(m2,0), a2s);
  for (int base=64; base<ne; base+=64){   // rare (deg>64)
    int i = base+lane; float x1=-1e30f, x2=-1e30f;
    if (i<ne){ int2 p = pk[r0+i]; float lab = __int_as_float(p.y); float2 av = alsP[p.x];
      x1 = lrelu(av.x + aldd.x + c1*lab); x2 = lrelu(av.y + aldd.y + c2*lab); }
    for (int o=32;o>0;o>>=1){ x1 = fmaxf(x1,__shfl_down(x1,o)); x2 = fmaxf(x2,__shfl_down(x2,o)); }
    m1 = fmaxf(m1, __shfl(x1,0)); m2 = fmaxf(m2, __shfl(x2,0));
  }
  float e1s = __expf(a1s-m1), e2s = __expf(a2s-m2);
  float z1 = e1s, z2 = e2s;
  bool lo = lane < 32;
  uint2 hv = hgI[d*64 + lane];
  float ws0 = lo ? e1s : e2s;
  float ac0 = ws0*b2f((ushort)(hv.x&0xffff));
  float ac1 = ws0*b2f((ushort)(hv.x>>16));
  float ac2 = ws0*b2f((ushort)(hv.y&0xffff));
  float ac3 = ws0*b2f((ushort)(hv.y>>16));
  {
    float e1 = (lane<ne) ? __expf(a1c-m1) : 0.f;
    float e2 = (lane<ne) ? __expf(a2c-m2) : 0.f;
    int lim = ne < 64 ? ne : 64;
    for (int j = 0; j < lim; j += 4){
      int i1 = (j+1<lim)? j+1 : lim-1;
      int i2 = (j+2<lim)? j+2 : lim-1;
      int i3 = (j+3<lim)? j+3 : lim-1;
      float f1a=__shfl(e1,j),   f1b=__shfl(e1,i1),  f1c=__shfl(e1,i2),  f1d=__shfl(e1,i3);
      float f2a=__shfl(e2,j),   f2bb=__shfl(e2,i1), f2c=__shfl(e2,i2),  f2d=__shfl(e2,i3);
      int   sa=__shfl(srcc,j),  sb=__shfl(srcc,i1), sc=__shfl(srcc,i2), sd=__shfl(srcc,i3);
      if (j+1>=lim){ f1b = 0.f; f2bb = 0.f; }
      if (j+2>=lim){ f1c = 0.f; f2c = 0.f; }
      if (j+3>=lim){ f1d = 0.f; f2d = 0.f; }
      uint2 va = hgI[(long)sa*64 + lane];
      uint2 vb = hgI[(long)sb*64 + lane];
      uint2 vc = hgI[(long)sc*64 + lane];
      uint2 vd = hgI[(long)sd*64 + lane];
      z1 += f1a+f1b+f1c+f1d; z2 += f2a+f2bb+f2c+f2d;
      float fa = lo ? f1a : f2a, fb = lo ? f1b : f2bb, fc = lo ? f1c : f2c, fd = lo ? f1d : f2d;
      ac0 += fa*b2f((ushort)(va.x&0xffff)) + fb*b2f((ushort)(vb.x&0xffff))
           + fc*b2f((ushort)(vc.x&0xffff)) + fd*b2f((ushort)(vd.x&0xffff));
      ac1 += fa*b2f((ushort)(va.x>>16)) + fb*b2f((ushort)(vb.x>>16))
           + fc*b2f((ushort)(vc.x>>16)) + fd*b2f((ushort)(vd.x>>16));
      ac2 += fa*b2f((ushort)(va.y&0xffff)) + fb*b2f((ushort)(vb.y&0xffff))
           + fc*b2f((ushort)(vc.y&0xffff)) + fd*b2f((ushort)(vd.y&0xffff));
      ac3 += fa*b2f((ushort)(va.y>>16)) + fb*b2f((ushort)(vb.y>>16))
           + fc*b2f((ushort)(vc.y>>16)) + fd*b2f((ushort)(vd.y>>16));
    }
  }
  for (int base=64; base<ne; base+=64){   // rare
    int i = base+lane; float e1=0.f, e2=0.f; int src = 0;
    if (i<ne){ int2 p = pk[r0+i]; float lab = __int_as_float(p.y); float2 av = alsP[p.x];
      e1 = __expf(lrelu(av.x + aldd.x + c1*lab)-m1);
      e2 = __expf(lrelu(av.y + aldd.y + c2*lab)-m2);
      src = p.x; }
    int lim2 = (ne-base < 64) ? (ne-base) : 64;
    for (int j2=0;j2<lim2;++j2){
      float f1 = __shfl(e1,j2), f2 = __shfl(e2,j2); int sj = __shfl(src,j2);
      z1 += f1; z2 += f2;
      uint2 vv = hgI[(long)sj*64 + lane];
      float f = lo ? f1 : f2;
      ac0 += f*b2f((ushort)(vv.x&0xffff));
      ac1 += f*b2f((ushort)(vv.x>>16));
      ac2 += f*b2f((ushort)(vv.y&0xffff));
      ac3 += f*b2f((ushort)(vv.y>>16));
    }
  }
  float iz = lo ? 1.f/(z1+1e-16f) : 1.f/(z2+1e-16f);
  ac0 *= iz; ac1 *= iz; ac2 *= iz; ac3 *= iz;
  int pl = lane ^ 32;
  float p0 = __shfl(ac0, pl), p1 = __shfl(ac1, pl), p2 = __shfl(ac2, pl), p3 = __shfl(ac3, pl);
  if (lo){
    float4 bb1 = ((const float4*)b1)[lane];
    float4 bb2 = ((const float4*)b2v)[lane];
    float4 ef  = ((const float4*)(entf + d*128))[lane];
    float4 o;
    o.x = ac0 + p0 + bb1.x + bb2.x + ef.x;
    o.y = ac1 + p1 + bb1.y + bb2.y + ef.y;
    o.z = ac2 + p2 + bb1.z + bb2.z + ef.z;
    o.w = ac3 + p3 + bb1.w + bb2.w + ef.w;
    ((float4*)(out + d*128))[lane] = o;
  }
}

// ---------------- host ----------------

extern "C" void kernel_launch(void* const* d_in, const int* in_sizes, int n_in,
                              void* d_out, int out_size, void* d_ws, size_t ws_size,
                              hipStream_t stream) {
  const int*   trip = (const int*)d_in[0];
  const int*   ee   = (const int*)d_in[1];
  const float* eel  = (const float*)d_in[2];
  const int*   ve   = (const int*)d_in[3];
  const float* att  = (const float*)d_in[5];
  const float* valf = (const float*)d_in[6];
  const float* entf = (const float*)d_in[7];
  const float* W    = (const float*)d_in[8];
  const float* G1   = (const float*)d_in[9];
  const float* g1b  = (const float*)d_in[10];
  const float* G2   = (const float*)d_in[11];
  const float* g2b  = (const float*)d_in[12];
  const float* Wl1  = (const float*)d_in[13];
  const float* as1v = (const float*)d_in[14];
  const float* ad1v = (const float*)d_in[15];
  const float* We1  = (const float*)d_in[16];
  const float* ae1  = (const float*)d_in[17];
  const float* b1   = (const float*)d_in[18];
  const float* Wl2  = (const float*)d_in[19];
  const float* as2v = (const float*)d_in[20];
  const float* ad2v = (const float*)d_in[21];
  const float* We2  = (const float*)d_in[22];
  const float* ae2  = (const float*)d_in[23];
  const float* b2   = (const float*)d_in[24];

  long T    = in_sizes[0]/3;
  long E1   = in_sizes[1]/2;
  long E2   = in_sizes[3]/2;
  long NA   = in_sizes[5]/128;
  long NV   = in_sizes[6]/128;
  long NEnt = in_sizes[7]/128;
  long N    = NEnt + T;

  size_t off = 0;
  auto alloc = [&](size_t bytes)->char*{
    char* p = (char*)d_ws + off; off = (off + bytes + 255) & ~(size_t)255; return p;
  };
  ushort* nodes0 = (ushort*)alloc((size_t)N*128*2);   // later reused as hgI (NEnt*256 ushorts)
  ushort* y1     = (ushort*)alloc((size_t)N*128*2);   // valP overlays this before y1 is written
  ushort* y2     = (ushort*)alloc((size_t)NEnt*128*2);
  float*  attP   = (float*)alloc((size_t)NA*128*4);
  int*    degi   = (int*)alloc(N*4);
  float*  dinv   = (float*)alloc(N*4);
  int*    cntE   = (int*)alloc(NEnt*4);
  float*  loopS  = (float*)alloc(NEnt*4);
  float*  loopA  = (float*)alloc(NEnt*4);
  float2* alsP   = (float2*)alloc(NEnt*8);
  float2* aldP   = (float2*)alloc(NEnt*8);
  float*  rs     = (float*)alloc(NEnt*4);
  int*    rpV    = (int*)alloc((N+1)*4);
  int*    curV   = (int*)alloc(N*4);
  int2*   pkV    = (int2*)alloc((size_t)E2*8);
  int*    rpE    = (int*)alloc((NEnt+1)*4);
  int*    curE   = (int*)alloc(NEnt*4);
  int2*   pkE    = (int2*)alloc((size_t)E1*8);
  int*    bsumV  = (int*)alloc(512*4);
  int*    boffV  = (int*)alloc(512*4);
  int*    bsumE  = (int*)alloc(512*4);
  int*    boffE  = (int*)alloc(512*4);
  ushort* Wvt    = (ushort*)alloc(16384*2);
  float*  P      = (float*)alloc(16384*4);
  ushort* M1t    = (ushort*)alloc(16384*2);
  ushort* M2t    = (ushort*)alloc(16384*2);
  float*  u1     = (float*)alloc(128*4);
  float*  v1     = (float*)alloc(128*4);
  float*  u2     = (float*)alloc(128*4);
  float*  v2     = (float*)alloc(128*4);
  float*  csc    = (float*)alloc(256);

  ushort* valP = y1;                 // dead before y1 is written
  ushort* hgI  = nodes0;             // dead after y1 aggregation

  auto cdiv = [](long a, long b)->int{ return (int)((a + b - 1)/b); };
  int nbV = cdiv(N, 1024), nbE = cdiv(NEnt, 1024);
  long Em = (E1 > E2) ? E1 : E2;

  // degrees / loop_attr (fused)
  k_zero<<<cdiv(N,256),256,0,stream>>>(degi, N, cntE, loopS, NEnt);
  k_deg<<<cdiv(Em,256),256,0,stream>>>(ve, E2, degi, ee, eel, E1, cntE, loopS);
  k_dinv<<<cdiv(N,256),256,0,stream>>>(degi, dinv, N, cntE, loopS, loopA, NEnt);

  // CSR build (V and E fused per stage)
  k_scan1_2<<<nbV+nbE,256,0,stream>>>(degi, N, rpV, bsumV, nbV, cntE, NEnt, rpE, bsumE);
  k_scan2_2<<<2,512,0,stream>>>(bsumV, boffV, nbV, bsumE, boffE, nbE);
  int nb3V = cdiv(N+1,256), nb3E = cdiv(NEnt+1,256);
  k_scan3_2<<<nb3V+nb3E,256,0,stream>>>(rpV, curV, boffV, N, (int)E2, nb3V, rpE, curE, boffE, NEnt, (int)E1);
  k_scatter2<<<cdiv(Em,256),256,0,stream>>>(ve, E2, dinv, curV, pkV, ee, eel, E1, curE, pkE);

  // tiny weight chains fused: wvt | mm128 | uv | csc | attP, then both Mt
  int nbAtt = cdiv(NA*128,256);
  k_tiny1<<<130+nbAtt,256,0,stream>>>(W, Wvt, G1, G2, P, g1b, g2b, Wl1, Wl2,
                                      u1, v1, u2, v2, We1, ae1, We2, ae2, csc, att, attP, NA);
  k_mmt2<<<128,256,0,stream>>>(P, Wl1, Wl2, M1t, M2t);

  // nodes0 (bf16): ent rows = ent_feats; val rows = attP[a] + (valf@Wv)[v]
  k_gemm<true><<<cdiv(NV,128),256,0,stream>>>(valf, Wvt, valP, NV, 128, 0, nullptr, nullptr, nullptr);
  int nbCast = cdiv(NEnt*32,256);
  k_cast_gather<<<nbCast+cdiv(T,4),256,0,stream>>>(entf, nodes0, NEnt*32, nbCast, trip, attP, valP, T, NEnt);

  // y1 = A(nodes0) over all N ; y2 = A(y1) over NEnt rows (+rowsum rs)
  k_agg<<<cdiv(N,4),256,0,stream>>>(rpV, pkV, nodes0, dinv, y1, nullptr, N);
  k_agg<<<cdiv(NEnt,4),256,0,stream>>>(rpV, pkV, y1, dinv, y2, rs, NEnt);

  // hgI rows = [ y2@M1 + rs*u1 + v1 | y2@M2 + rs*u2 + v2 ] in ONE launch
  int nbF = cdiv(NEnt,128);
  k_gemm2<<<2*nbF,256,0,stream>>>(y2, M1t, M2t, (ushort*)hgI, NEnt, nbF, u1, v1, u2, v2, rs);

  // GAT attention scalars + fused dual-layer aggregation -> final output
  k_dots<<<cdiv(NEnt,4),256,0,stream>>>((const uint2*)hgI, as1v, ad1v, as2v, ad2v, alsP, aldP, NEnt);
  k_gat_csr<<<cdiv(NEnt,4),256,0,stream>>>(rpE, pkE, (const uint2*)hgI, alsP, aldP,
                                           loopA, csc, b1, b2, entf, (float*)d_out, NEnt);
}